// Round 4
// baseline (10303.085 us; speedup 1.0000x reference)
//
#include <hip/hip_runtime.h>

#define B_    4
#define N1_   16384
#define M1_   2048
#define M2_   512
#define KNN_  32
#define PROJ_ 64
#define C1_   128
#define C2_   256
#define FSPLIT_ 4   // CUs cooperating on one batch's FPS-1

__device__ __forceinline__ float sqdist_exact(float px, float py, float pz,
                                              float cx, float cy, float cz) {
    // Must match numpy: ((dx*dx + dy*dy) + dz*dz), no FMA contraction.
    float dx = __fsub_rn(px, cx);
    float dy = __fsub_rn(py, cy);
    float dz = __fsub_rn(pz, cz);
    return __fadd_rn(__fadd_rn(__fmul_rn(dx, dx), __fmul_rn(dy, dy)), __fmul_rn(dz, dz));
}

// ---------------- projection: feats0[b,n,c] = xyz[b,n,:] @ Wp + bp ----------------
__global__ void __launch_bounds__(256)
proj_kernel(const float* __restrict__ xyz, const float* __restrict__ Wp,
            const float* __restrict__ bp, float* __restrict__ feats0) {
    int tid = blockIdx.x * 256 + threadIdx.x;
    int c = tid & (PROJ_ - 1);
    int pn = tid >> 6;
    if (pn >= B_ * N1_) return;
    const float* p = xyz + (size_t)pn * 3;
    float acc = p[0] * Wp[0 * PROJ_ + c];
    acc = __fmaf_rn(p[1], Wp[1 * PROJ_ + c], acc);
    acc = __fmaf_rn(p[2], Wp[2 * PROJ_ + c], acc);
    feats0[tid] = acc + bp[c];
}

// ---------------- farthest point sampling ----------------
// key = (f32bits(dmin) << 32) | ~gidx : u64 max == max value, tie -> min index
// (exactly jnp.argmax first-occurrence semantics; d >= 0 so f32 bits monotone).
// Round-8: r0-r3 all pinned per-iter at ~3850-4900 cyc with VGPR_Count ~92-104
// vs ~170 live values -> allocator keeps ~1/3 of state out of arch VGPRs and
// pays per-iter move/spill traffic (~300 extra VALU inst/wave/iter observed).
// Fix structurally: split each batch's FPS across FSPLIT_=4 CUs. PPT drops
// 32->8 (32 pinned floats/thread, ~60 VGPR: pressure pathology impossible)
// and the phase-A issue wall drops 4x. Blocks exchange their block-best u64
// key per iteration through zero-init global slots (agent-scope atomics);
// winner = max of 4 keys == single-block reduce bit-exactly.
// Key is provably nonzero (low word ~gi, gi < 16384) -> slot==0 means
// "not yet written"; slots are hipMemsetAsync'd to 0 each launch.
template<int CTRL, int RM>
__device__ __forceinline__ unsigned long long dpp_umax64(unsigned long long pk) {
    unsigned lo = (unsigned)__builtin_amdgcn_update_dpp(
        0, (int)(unsigned)pk, CTRL, RM, 0xf, true);
    unsigned hi = (unsigned)__builtin_amdgcn_update_dpp(
        0, (int)(unsigned)(pk >> 32), CTRL, RM, 0xf, true);
    unsigned long long o = ((unsigned long long)hi << 32) | (unsigned long long)lo;
    return (o > pk) ? o : pk;
}

__device__ __forceinline__ unsigned long long wave_max_key(unsigned long long pk) {
    pk = dpp_umax64<0x111, 0xf>(pk);   // row_shr:1
    pk = dpp_umax64<0x112, 0xf>(pk);   // row_shr:2
    pk = dpp_umax64<0x114, 0xf>(pk);   // row_shr:4
    pk = dpp_umax64<0x118, 0xf>(pk);   // row_shr:8
    pk = dpp_umax64<0x142, 0xa>(pk);   // row_bcast15 -> rows 1,3
    pk = dpp_umax64<0x143, 0xc>(pk);   // row_bcast31 -> rows 2,3
    return pk;                          // lane 63 holds the wave max
}

// ---- multi-block FPS (fps1): NS blocks per batch cooperate ----
template<int N, int M, int NT, int NS>
__device__ __forceinline__ void fps_split_body(const float* __restrict__ pts,
                                               float* __restrict__ centers,
                                               unsigned long long* __restrict__ slots) {
    constexpr int NL  = N / NS;       // points per block
    constexpr int PPT = NL / NT;      // points per thread (8)
    constexpr int NW  = NT / 64;
    const int bb = blockIdx.x;
    const int b  = bb / NS;           // batch
    const int h  = bb % NS;           // split id
    const int t = threadIdx.x;
    const int w = t >> 6;
    const int lane = t & 63;
    const float* P = pts + (size_t)b * N * 3;
    float* C = centers + (size_t)b * M * 3;
    unsigned long long* S = slots + (size_t)b * M * NS;

    float px[PPT], py[PPT], pz[PPT], dmin[PPT];
#pragma unroll
    for (int k = 0; k < PPT; ++k) {
        int j = h * NL + k * NT + t;
        px[k] = P[j * 3 + 0];
        py[k] = P[j * 3 + 1];
        pz[k] = P[j * 3 + 2];
        dmin[k] = 1e10f;
    }
    // Pin: values become asm outputs -> compiler cannot rematerialize the loads.
#pragma unroll
    for (int k = 0; k < PPT; ++k)
        asm volatile("" : "+v"(px[k]), "+v"(py[k]), "+v"(pz[k]), "+v"(dmin[k]));

    __shared__ alignas(16) unsigned long long wkey[2][NW];  // parity double-buffered
    __shared__ alignas(16) float cbuf[M * 3];               // used by h==0 only

    float cx = P[0], cy = P[1], cz = P[2];

    for (int m = 0; m < M; ++m) {
        if (h == 0 && t == 0) {
            cbuf[m * 3 + 0] = cx; cbuf[m * 3 + 1] = cy; cbuf[m * 3 + 2] = cz;
        }
        if (m == M - 1) break;
        const int par = m & 1;
        // ---- A: update dmin over my 8 pts; per-lane argmax (first k on ties)
        float bv = -1.0f; int bk = 0;
#pragma unroll
        for (int k = 0; k < PPT; ++k) {
            float d  = sqdist_exact(px[k], py[k], pz[k], cx, cy, cz);
            float nd = fminf(dmin[k], d);
            dmin[k] = nd;
            bool gt = nd > bv;
            bv = gt ? nd : bv;
            bk = gt ? k : bk;
        }
        // ---- B: pack (value, ~global_idx); wave max via DPP scan
        unsigned gi = (unsigned)(h * NL + bk * NT + t);
        unsigned long long pk =
            ((unsigned long long)__float_as_uint(bv) << 32) | (unsigned)(~gi);
        pk = wave_max_key(pk);
        if (lane == 63) wkey[par][w] = pk;
        __syncthreads();                   // the ONLY barrier per iter
        // ---- C: cross-wave tree reduce of NW keys (uniform, every thread)
        unsigned long long v[NW];
#pragma unroll
        for (int i = 0; i < NW; ++i) v[i] = wkey[par][i];
#pragma unroll
        for (int s = NW / 2; s > 0; s >>= 1)
#pragma unroll
            for (int i = 0; i < s; ++i) v[i] = (v[i + s] > v[i]) ? v[i + s] : v[i];
        unsigned long long best = v[0];    // block-local best
        // ---- X: exchange with NS-1 sibling blocks via global slots
        if (t == 0)
            __hip_atomic_store(&S[(size_t)m * NS + h], best,
                               __ATOMIC_RELEASE, __HIP_MEMORY_SCOPE_AGENT);
#pragma unroll
        for (int p = 1; p < NS; ++p) {
            const int q = h ^ p;
            unsigned long long kp;
            do {
                kp = __hip_atomic_load(&S[(size_t)m * NS + q],
                                       __ATOMIC_ACQUIRE, __HIP_MEMORY_SCOPE_AGENT);
            } while (kp == 0ull);
            best = (kp > best) ? kp : best;
        }
        // ---- D: winner coords via uniform load (cache-resident)
        const unsigned widx = ~(unsigned)best;
        const float* cp = P + (size_t)widx * 3;
        cx = cp[0]; cy = cp[1]; cz = cp[2];
    }
    if (h == 0) {
        __syncthreads();
        // flush centers LDS -> global, coalesced float4
#pragma unroll 1
        for (int i = t; i < (M * 3) / 4; i += NT)
            ((float4*)C)[i] = ((const float4*)cbuf)[i];
    }
}

__global__ __attribute__((amdgpu_flat_work_group_size(512, 512)))
void fps1_kernel(const float* __restrict__ pts, float* __restrict__ centers,
                 unsigned long long* __restrict__ slots) {
    fps_split_body<N1_, M1_, 512, FSPLIT_>(pts, centers, slots);
}

// ---- single-block FPS (fps2): r2 structure, PPT=8 already ----
template<int N, int M, int NT>
__device__ __forceinline__ void fps_body(const float* __restrict__ pts,
                                         float* __restrict__ centers) {
    constexpr int PPT = N / NT;
    constexpr int NW  = NT / 64;
    const int b = blockIdx.x;
    const int t = threadIdx.x;
    const int w = t >> 6;
    const int lane = t & 63;
    const float* P = pts + (size_t)b * N * 3;
    float* C = centers + (size_t)b * M * 3;

    float px[PPT], py[PPT], pz[PPT], dmin[PPT];
#pragma unroll
    for (int k = 0; k < PPT; ++k) {
        int j = k * NT + t;
        px[k] = P[j * 3 + 0];
        py[k] = P[j * 3 + 1];
        pz[k] = P[j * 3 + 2];
        dmin[k] = 1e10f;
    }
#pragma unroll
    for (int k = 0; k < PPT; ++k)
        asm volatile("" : "+v"(px[k]), "+v"(py[k]), "+v"(pz[k]), "+v"(dmin[k]));

    __shared__ alignas(16) unsigned long long wkey[2][NW];
    __shared__ alignas(16) float cbuf[M * 3];

    float cx = P[0], cy = P[1], cz = P[2];

    for (int m = 0; m < M; ++m) {
        if (t == 0) {
            cbuf[m * 3 + 0] = cx; cbuf[m * 3 + 1] = cy; cbuf[m * 3 + 2] = cz;
        }
        if (m == M - 1) break;
        const int par = m & 1;
        float bv = -1.0f; int bk = 0;
#pragma unroll
        for (int k = 0; k < PPT; ++k) {
            float d  = sqdist_exact(px[k], py[k], pz[k], cx, cy, cz);
            float nd = fminf(dmin[k], d);
            dmin[k] = nd;
            bool gt = nd > bv;
            bv = gt ? nd : bv;
            bk = gt ? k : bk;
        }
        unsigned gi = (unsigned)(bk * NT + t);
        unsigned long long pk =
            ((unsigned long long)__float_as_uint(bv) << 32) | (unsigned)(~gi);
        pk = wave_max_key(pk);
        if (lane == 63) wkey[par][w] = pk;
        __syncthreads();
        unsigned long long v[NW];
#pragma unroll
        for (int i = 0; i < NW; ++i) v[i] = wkey[par][i];
#pragma unroll
        for (int s = NW / 2; s > 0; s >>= 1)
#pragma unroll
            for (int i = 0; i < s; ++i) v[i] = (v[i + s] > v[i]) ? v[i + s] : v[i];
        const unsigned widx = ~(unsigned)v[0];
        const float* cp = P + (size_t)widx * 3;
        cx = cp[0]; cy = cp[1]; cz = cp[2];
    }
    __syncthreads();
#pragma unroll 1
    for (int i = t; i < (M * 3) / 4; i += NT)
        ((float4*)C)[i] = ((const float4*)cbuf)[i];
}

__global__ __attribute__((amdgpu_flat_work_group_size(256, 256)))
__attribute__((amdgpu_waves_per_eu(1, 4)))
void fps2_kernel(const float* __restrict__ pts, float* __restrict__ centers) {
    fps_body<M1_, M2_, 256>(pts, centers);
}

// ---------------- exact kNN (top-32 smallest sq-dist, tie -> smaller index) ----------------
// radix-select over float bit patterns (all d >= 0 -> monotone in uint bits)
template<int N, int M>
__global__ void __launch_bounds__(64)
knn_kernel(const float* __restrict__ pts, const float* __restrict__ centers,
           int* __restrict__ nidx) {
    constexpr int K = KNN_;
    constexpr int CAP = 224;
    const int bm = blockIdx.x;
    const int b = bm / M;
    const int lane = threadIdx.x;
    const float* P = pts + (size_t)b * N * 3;
    const float* c = centers + (size_t)bm * 3;
    const float cx = c[0], cy = c[1], cz = c[2];
    int* out = nidx + (size_t)bm * K;

    __shared__ int hist[2048];
    __shared__ unsigned int eqk[CAP];
    __shared__ int eqi[CAP];
    __shared__ int cnt_less, cnt_eq;

    unsigned int prefix = 0; int pbits = 0;
    unsigned int Tlo = 0; unsigned long long Thi = 0x100000000ull;
    int L = 0, target = K, Cbin = N;

    for (int round = 0; round < 3; ++round) {
        const int bits  = (round < 2) ? 11 : 10;
        const int nbins = 1 << bits;
        const int shift = 32 - pbits - bits;
        for (int i = lane; i < nbins; i += 64) hist[i] = 0;
        __syncthreads();
        for (int j = lane; j < N; j += 64) {
            float d = sqdist_exact(P[j * 3], P[j * 3 + 1], P[j * 3 + 2], cx, cy, cz);
            unsigned int key = __float_as_uint(d);
            if (key >= Tlo && (unsigned long long)key < Thi)
                atomicAdd(&hist[(key >> shift) & (nbins - 1)], 1);
        }
        __syncthreads();
        const int per = nbins / 64;
        int s = 0;
        for (int i = 0; i < per; ++i) s += hist[lane * per + i];
        int cum = s;
        for (int off = 1; off < 64; off <<= 1) {
            int o = __shfl_up(cum, off);
            if (lane >= off) cum += o;
        }
        int cumex = cum - s;
        bool has = (cumex < target) && (cum >= target);
        unsigned long long ball = __ballot(has);
        int src = __ffsll(ball) - 1;
        int binsel = 0, Ladd = 0, bincnt = 0;
        if (lane == src) {
            int acc = cumex;
            for (int i = 0; i < per; ++i) {
                int h = hist[lane * per + i];
                if (acc + h >= target) { binsel = lane * per + i; Ladd = acc; bincnt = h; break; }
                acc += h;
            }
        }
        binsel = __shfl(binsel, src);
        Ladd   = __shfl(Ladd, src);
        bincnt = __shfl(bincnt, src);
        L += Ladd;
        target -= Ladd;
        prefix = (prefix << bits) | (unsigned int)binsel;
        pbits += bits;
        Tlo = prefix << (32 - pbits);
        Thi = ((unsigned long long)prefix + 1ull) << (32 - pbits);
        Cbin = bincnt;
        __syncthreads();
        if (Cbin <= CAP) break;
    }

    if (lane == 0) { cnt_less = 0; cnt_eq = 0; }
    __syncthreads();

    if (Cbin <= CAP) {
        for (int j = lane; j < N; j += 64) {
            float d = sqdist_exact(P[j * 3], P[j * 3 + 1], P[j * 3 + 2], cx, cy, cz);
            unsigned int key = __float_as_uint(d);
            if (key < Tlo) {
                int p = atomicAdd(&cnt_less, 1);
                out[p] = j;
            } else if ((unsigned long long)key < Thi) {
                int p = atomicAdd(&cnt_eq, 1);
                eqk[p] = key; eqi[p] = j;
            }
        }
        __syncthreads();
        const int E = cnt_eq;
        for (int e = lane; e < E; e += 64) {
            unsigned int ke = eqk[e]; int ie = eqi[e];
            int rank = 0;
            for (int f = 0; f < E; ++f) {
                unsigned int kf = eqk[f]; int jf = eqi[f];
                rank += (kf < ke || (kf == ke && jf < ie)) ? 1 : 0;
            }
            if (rank < target) out[L + rank] = ie;
        }
    } else {
        // pbits==32: giant tie class at exact key Tlo -> take smallest indices in order
        int cnt = 0;
        for (int jb = 0; jb < N; jb += 64) {
            int j = jb + lane;
            float d = sqdist_exact(P[j * 3], P[j * 3 + 1], P[j * 3 + 2], cx, cy, cz);
            unsigned int key = __float_as_uint(d);
            if (key < Tlo) {
                int p = atomicAdd(&cnt_less, 1);
                out[p] = j;
            }
            bool eq = (key == Tlo);
            unsigned long long mb = __ballot(eq);
            int below = __popcll(mb & ((1ull << lane) - 1ull));
            if (eq && (cnt + below) < target) out[L + cnt + below] = j;
            cnt += (int)__popcll(mb);
        }
    }
}

// ---------------- grouped 2-layer MLP + max-pool over 32 neighbors ----------------
// g stored as [nf(FD) | rel(3) | pad], Wa rows remapped accordingly.
template<int NPTS, int FD, int CO, int M>
__global__ void __launch_bounds__(CO)
group_mlp_kernel(const float* __restrict__ pts, const float* __restrict__ feats,
                 const float* __restrict__ centers, const int* __restrict__ nidx,
                 const float* __restrict__ Wa, const float* __restrict__ ba,
                 const float* __restrict__ Wb, const float* __restrict__ bb,
                 float* __restrict__ outf) {
    constexpr int KN = KNN_;
    constexpr int GS = FD + 4;
    const int bm = blockIdx.x;
    const int b = bm / M;
    const int t = threadIdx.x;
    __shared__ float g[KN][GS];
    __shared__ float h1[KN][CO];
    const int* nb = nidx + (size_t)bm * KN;
    const float* cen = centers + (size_t)bm * 3;
    const float cx = cen[0], cy = cen[1], cz = cen[2];
    {
        constexpr int PARTS = CO / KN;        // 4 (L1) or 8 (L2)
        constexpr int CHUNK = FD / PARTS;     // 16
        const int kk = t / PARTS;
        const int q  = t % PARTS;
        const int j  = nb[kk];
        const float* f = feats + ((size_t)b * NPTS + j) * FD + q * CHUNK;
        float* gr = &g[kk][q * CHUNK];
#pragma unroll
        for (int u = 0; u < CHUNK / 4; ++u)
            *(float4*)(gr + 4 * u) = *(const float4*)(f + 4 * u);
        if (q == 0) {
            const float* p = pts + ((size_t)b * NPTS + j) * 3;
            g[kk][FD + 0] = __fsub_rn(p[0], cx);
            g[kk][FD + 1] = __fsub_rn(p[1], cy);
            g[kk][FD + 2] = __fsub_rn(p[2], cz);
            g[kk][FD + 3] = 0.f;
        }
    }
    __syncthreads();
    const int o = t;
    float acc[KN];
#pragma unroll
    for (int k = 0; k < KN; ++k) acc[k] = ba[o];
    for (int s4 = 0; s4 < FD / 4; ++s4) {   // nf part: stored s -> Wa row s+3
        const float w0 = Wa[(4 * s4 + 3) * CO + o];
        const float w1 = Wa[(4 * s4 + 4) * CO + o];
        const float w2 = Wa[(4 * s4 + 5) * CO + o];
        const float w3 = Wa[(4 * s4 + 6) * CO + o];
#pragma unroll
        for (int k = 0; k < KN; ++k) {
            float4 gv = *(const float4*)&g[k][4 * s4];
            acc[k] = __fmaf_rn(gv.x, w0, acc[k]);
            acc[k] = __fmaf_rn(gv.y, w1, acc[k]);
            acc[k] = __fmaf_rn(gv.z, w2, acc[k]);
            acc[k] = __fmaf_rn(gv.w, w3, acc[k]);
        }
    }
    {
        const float w0 = Wa[0 * CO + o];
        const float w1 = Wa[1 * CO + o];
        const float w2 = Wa[2 * CO + o];
#pragma unroll
        for (int k = 0; k < KN; ++k) {
            float4 gv = *(const float4*)&g[k][FD];
            acc[k] = __fmaf_rn(gv.x, w0, acc[k]);
            acc[k] = __fmaf_rn(gv.y, w1, acc[k]);
            acc[k] = __fmaf_rn(gv.z, w2, acc[k]);
        }
    }
#pragma unroll
    for (int k = 0; k < KN; ++k) h1[k][o] = fmaxf(acc[k], 0.f);
    __syncthreads();
#pragma unroll
    for (int k = 0; k < KN; ++k) acc[k] = bb[o];
    for (int s4 = 0; s4 < CO / 4; ++s4) {
        const float w0 = Wb[(4 * s4 + 0) * CO + o];
        const float w1 = Wb[(4 * s4 + 1) * CO + o];
        const float w2 = Wb[(4 * s4 + 2) * CO + o];
        const float w3 = Wb[(4 * s4 + 3) * CO + o];
#pragma unroll
        for (int k = 0; k < KN; ++k) {
            float4 hv = *(const float4*)&h1[k][4 * s4];
            acc[k] = __fmaf_rn(hv.x, w0, acc[k]);
            acc[k] = __fmaf_rn(hv.y, w1, acc[k]);
            acc[k] = __fmaf_rn(hv.z, w2, acc[k]);
            acc[k] = __fmaf_rn(hv.w, w3, acc[k]);
        }
    }
    float mx = 0.f;
#pragma unroll
    for (int k = 0; k < KN; ++k) mx = fmaxf(mx, fmaxf(acc[k], 0.f));
    outf[(size_t)bm * CO + o] = mx;
}

// ---------------- global head: [max|mean] -> relu(g@Wd1+b) -> @Wd2+b ----------------
__global__ void __launch_bounds__(256)
head_kernel(const float* __restrict__ feats2,
            const float* __restrict__ Wd1, const float* __restrict__ bd1,
            const float* __restrict__ Wd2, const float* __restrict__ bd2,
            float* __restrict__ outp) {
    const int b = blockIdx.x, t = threadIdx.x;
    __shared__ float gsh[2 * C2_];
    __shared__ float hsh[512];
    const float* F = feats2 + (size_t)b * M2_ * C2_;
    float mx = -1e30f, sm = 0.f;
    for (int r = 0; r < M2_; ++r) {
        float v = F[r * C2_ + t];
        mx = fmaxf(mx, v);
        sm += v;
    }
    gsh[t] = mx;
    gsh[C2_ + t] = sm * (1.0f / (float)M2_);
    __syncthreads();
#pragma unroll
    for (int oo = 0; oo < 2; ++oo) {
        const int o = t + oo * 256;
        float acc = bd1[o];
        for (int i = 0; i < 512; ++i)
            acc = __fmaf_rn(gsh[i], Wd1[i * 512 + o], acc);
        hsh[o] = fmaxf(acc, 0.f);
    }
    __syncthreads();
    float acc = bd2[t];
    for (int i = 0; i < 512; ++i)
        acc = __fmaf_rn(hsh[i], Wd2[i * 256 + t], acc);
    outp[b * 256 + t] = acc;
}

extern "C" void kernel_launch(void* const* d_in, const int* in_sizes, int n_in,
                              void* d_out, int out_size, void* d_ws, size_t ws_size,
                              hipStream_t stream) {
    const float* xyz = (const float*)d_in[0];
    const float* Wp  = (const float*)d_in[1];
    const float* bp  = (const float*)d_in[2];
    const float* W1a = (const float*)d_in[3];
    const float* b1a = (const float*)d_in[4];
    const float* W1b = (const float*)d_in[5];
    const float* b1b = (const float*)d_in[6];
    const float* W2a = (const float*)d_in[7];
    const float* b2a = (const float*)d_in[8];
    const float* W2b = (const float*)d_in[9];
    const float* b2b = (const float*)d_in[10];
    const float* Wd1 = (const float*)d_in[11];
    const float* bd1 = (const float*)d_in[12];
    const float* Wd2 = (const float*)d_in[13];
    const float* bd2 = (const float*)d_in[14];
    float* out = (float*)d_out;

    char* ws = (char*)d_ws;
    size_t off = 0;
    auto alloc = [&](size_t bytes) { void* p = ws + off; off += (bytes + 255) & ~(size_t)255; return p; };
    float* feats0   = (float*)alloc((size_t)B_ * N1_ * PROJ_ * 4);
    float* centers1 = (float*)alloc((size_t)B_ * M1_ * 3 * 4);
    int*   nidx1    = (int*)  alloc((size_t)B_ * M1_ * KNN_ * 4);
    float* feats1   = (float*)alloc((size_t)B_ * M1_ * C1_ * 4);
    float* centers2 = (float*)alloc((size_t)B_ * M2_ * 3 * 4);
    int*   nidx2    = (int*)  alloc((size_t)B_ * M2_ * KNN_ * 4);
    float* feats2   = (float*)alloc((size_t)B_ * M2_ * C2_ * 4);
    const size_t slot_bytes = (size_t)B_ * M1_ * FSPLIT_ * 8;
    unsigned long long* slots = (unsigned long long*)alloc(slot_bytes);
    (void)in_sizes; (void)n_in; (void)out_size; (void)ws_size;

    // zero the FPS exchange slots every launch (graph replays must not see stale keys)
    hipMemsetAsync(slots, 0, slot_bytes, stream);

    proj_kernel<<<dim3(B_ * N1_ * PROJ_ / 256), dim3(256), 0, stream>>>(xyz, Wp, bp, feats0);
    fps1_kernel<<<dim3(B_ * FSPLIT_), dim3(512), 0, stream>>>(xyz, centers1, slots);
    knn_kernel<N1_, M1_><<<dim3(B_ * M1_), dim3(64), 0, stream>>>(xyz, centers1, nidx1);
    group_mlp_kernel<N1_, PROJ_, C1_, M1_><<<dim3(B_ * M1_), dim3(C1_), 0, stream>>>(
        xyz, feats0, centers1, nidx1, W1a, b1a, W1b, b1b, feats1);
    fps2_kernel<<<dim3(B_), dim3(256), 0, stream>>>(centers1, centers2);
    knn_kernel<M1_, M2_><<<dim3(B_ * M2_), dim3(64), 0, stream>>>(centers1, centers2, nidx2);
    group_mlp_kernel<M1_, C1_, C2_, M2_><<<dim3(B_ * M2_), dim3(C2_), 0, stream>>>(
        centers1, feats1, centers2, nidx2, W2a, b2a, W2b, b2b, feats2);
    head_kernel<<<dim3(B_), dim3(256), 0, stream>>>(feats2, Wd1, bd1, Wd2, bd2, out);
}

// Round 5
// 4337.697 us; speedup vs baseline: 2.3752x; 2.3752x over previous
//
#include <hip/hip_runtime.h>

#define B_    4
#define N1_   16384
#define M1_   2048
#define M2_   512
#define KNN_  32
#define PROJ_ 64
#define C1_   128
#define C2_   256

__device__ __forceinline__ float sqdist_exact(float px, float py, float pz,
                                              float cx, float cy, float cz) {
    // Must match numpy: ((dx*dx + dy*dy) + dz*dz), no FMA contraction.
    float dx = __fsub_rn(px, cx);
    float dy = __fsub_rn(py, cy);
    float dz = __fsub_rn(pz, cz);
    return __fadd_rn(__fadd_rn(__fmul_rn(dx, dx), __fmul_rn(dy, dy)), __fmul_rn(dz, dz));
}

// ---------------- projection: feats0[b,n,c] = xyz[b,n,:] @ Wp + bp ----------------
__global__ void __launch_bounds__(256)
proj_kernel(const float* __restrict__ xyz, const float* __restrict__ Wp,
            const float* __restrict__ bp, float* __restrict__ feats0) {
    int tid = blockIdx.x * 256 + threadIdx.x;
    int c = tid & (PROJ_ - 1);
    int pn = tid >> 6;
    if (pn >= B_ * N1_) return;
    const float* p = xyz + (size_t)pn * 3;
    float acc = p[0] * Wp[0 * PROJ_ + c];
    acc = __fmaf_rn(p[1], Wp[1 * PROJ_ + c], acc);
    acc = __fmaf_rn(p[2], Wp[2 * PROJ_ + c], acc);
    feats0[tid] = acc + bp[c];
}

// ---------------- farthest point sampling (both levels fused) ----------------
// Serial-latency-bound; 1 CU per batch (r4 proved cross-CU exchange is a net
// loss: agent-scope polling = 600-1500 cyc/iter cross-XCD round trips).
// key = (f32bits(dmin) << 32) | ~gidx : u64 max == max value, tie -> min index
// (exactly jnp.argmax first-occurrence semantics; d >= 0 so f32 bits monotone).
// Round-9 structure:
//  - r2 layout (NT=512, PPT=32, DPP wave scan, LDS centers staging) — best known;
//  - LEAN cross-wave reduce: 1 ds_read_b64/wave (lane reads wkey[lane&7]) +
//    3-step DPP max over lanes 0..7 + readlane -> SGPR widx -> scalar winner
//    load. Replaces 8 uniform ds_read_b64 + 7 u64 maxes per THREAD (64
//    LDS insts/CU post-barrier ~330 cyc) with 8/CU;
//  - fps level-2 fused into the same kernel: centers1 already staged in LDS,
//    stage 2 runs on the LDS copy (winner reads ~120 cyc vs ~200 global),
//    saving the fps2 launch + global round trip.
template<int CTRL, int RM>
__device__ __forceinline__ unsigned long long dpp_umax64(unsigned long long pk) {
    unsigned lo = (unsigned)__builtin_amdgcn_update_dpp(
        0, (int)(unsigned)pk, CTRL, RM, 0xf, true);
    unsigned hi = (unsigned)__builtin_amdgcn_update_dpp(
        0, (int)(unsigned)(pk >> 32), CTRL, RM, 0xf, true);
    unsigned long long o = ((unsigned long long)hi << 32) | (unsigned long long)lo;
    return (o > pk) ? o : pk;
}

__device__ __forceinline__ unsigned long long wave_max_key(unsigned long long pk) {
    pk = dpp_umax64<0x111, 0xf>(pk);   // row_shr:1
    pk = dpp_umax64<0x112, 0xf>(pk);   // row_shr:2
    pk = dpp_umax64<0x114, 0xf>(pk);   // row_shr:4
    pk = dpp_umax64<0x118, 0xf>(pk);   // row_shr:8
    pk = dpp_umax64<0x142, 0xa>(pk);   // row_bcast15 -> rows 1,3
    pk = dpp_umax64<0x143, 0xc>(pk);   // row_bcast31 -> rows 2,3
    return pk;                          // lane 63 holds the wave max
}

// Lean 8-key reduce: all lanes load wkey[lane&7] (one ds_read_b64 per wave,
// grouped-broadcast, conflict-free), 3-step DPP scan puts max(keys 0..7) in
// lane 7; readlane -> uniform. Bit-exact: u64 max is associative/commutative.
__device__ __forceinline__ unsigned reduce8_widx(const unsigned long long* wk,
                                                 int lane) {
    unsigned long long k8 = wk[lane & 7];
    k8 = dpp_umax64<0x111, 0xf>(k8);
    k8 = dpp_umax64<0x112, 0xf>(k8);
    k8 = dpp_umax64<0x114, 0xf>(k8);
    unsigned lo = (unsigned)__builtin_amdgcn_readlane((int)(unsigned)k8, 7);
    return ~lo;   // uniform (SGPR) winner index
}

__global__ __attribute__((amdgpu_flat_work_group_size(512, 512)))
__attribute__((amdgpu_waves_per_eu(2, 2)))
void fps_fused_kernel(const float* __restrict__ pts,
                      float* __restrict__ centers1,
                      float* __restrict__ centers2) {
    constexpr int NT = 512;
    constexpr int NW = NT / 64;          // 8
    constexpr int PPT1 = N1_ / NT;       // 32
    constexpr int PPT2 = M1_ / NT;       // 4
    const int b = blockIdx.x;
    const int t = threadIdx.x;
    const int w = t >> 6;
    const int lane = t & 63;
    const float* P = pts + (size_t)b * N1_ * 3;

    __shared__ alignas(16) unsigned long long wkey[2][NW];
    __shared__ alignas(16) float cb1[M1_ * 3];   // 24 KB, centers1 staging
    __shared__ alignas(16) float cb2[M2_ * 3];   //  6 KB, centers2 staging

    // ================= stage 1: FPS over global pts (N1 -> M1) =================
    {
        float px[PPT1], py[PPT1], pz[PPT1], dmin[PPT1];
#pragma unroll
        for (int k = 0; k < PPT1; ++k) {
            int j = k * NT + t;
            px[k] = P[j * 3 + 0];
            py[k] = P[j * 3 + 1];
            pz[k] = P[j * 3 + 2];
            dmin[k] = 1e10f;
        }
        // Pin: values become asm outputs -> compiler cannot rematerialize loads.
#pragma unroll
        for (int k = 0; k < PPT1; ++k)
            asm volatile("" : "+v"(px[k]), "+v"(py[k]), "+v"(pz[k]), "+v"(dmin[k]));

        float cx = P[0], cy = P[1], cz = P[2];

        for (int m = 0; m < M1_; ++m) {
            if (t == 0) {
                cb1[m * 3 + 0] = cx; cb1[m * 3 + 1] = cy; cb1[m * 3 + 2] = cz;
            }
            if (m == M1_ - 1) break;
            const int par = m & 1;
            // ---- A: update dmin; per-lane argmax (first k on ties via strict >)
            float bv = -1.0f; int bk = 0;
#pragma unroll
            for (int k = 0; k < PPT1; ++k) {
                float d  = sqdist_exact(px[k], py[k], pz[k], cx, cy, cz);
                float nd = fminf(dmin[k], d);
                dmin[k] = nd;
                bool gt = nd > bv;
                bv = gt ? nd : bv;
                bk = gt ? k : bk;
            }
            // ---- B: pack (value, ~gidx); wave max via DPP scan
            unsigned gi = (unsigned)(bk * NT + t);
            unsigned long long pk =
                ((unsigned long long)__float_as_uint(bv) << 32) | (unsigned)(~gi);
            pk = wave_max_key(pk);
            if (lane == 63) wkey[par][w] = pk;
            __syncthreads();               // the ONLY barrier per iter
            // ---- C: lean reduce -> uniform winner index
            const unsigned widx = reduce8_widx(wkey[par], lane);
            // ---- D: winner coords via scalar (uniform) load — L2-resident
            const float* cp = P + (size_t)widx * 3;
            cx = cp[0]; cy = cp[1]; cz = cp[2];
        }
    }
    __syncthreads();
    // flush centers1 LDS -> global, coalesced float4
#pragma unroll 1
    for (int i = t; i < (M1_ * 3) / 4; i += NT)
        ((float4*)(centers1 + (size_t)b * M1_ * 3))[i] = ((const float4*)cb1)[i];

    // ================= stage 2: FPS over cb1 in LDS (M1 -> M2) =================
    {
        float px[PPT2], py[PPT2], pz[PPT2], dmin[PPT2];
#pragma unroll
        for (int k = 0; k < PPT2; ++k) {
            int j = k * NT + t;
            px[k] = cb1[j * 3 + 0];
            py[k] = cb1[j * 3 + 1];
            pz[k] = cb1[j * 3 + 2];
            dmin[k] = 1e10f;
        }
#pragma unroll
        for (int k = 0; k < PPT2; ++k)
            asm volatile("" : "+v"(px[k]), "+v"(py[k]), "+v"(pz[k]), "+v"(dmin[k]));

        float cx = cb1[0], cy = cb1[1], cz = cb1[2];

        for (int m = 0; m < M2_; ++m) {
            if (t == 0) {
                cb2[m * 3 + 0] = cx; cb2[m * 3 + 1] = cy; cb2[m * 3 + 2] = cz;
            }
            if (m == M2_ - 1) break;
            const int par = m & 1;
            float bv = -1.0f; int bk = 0;
#pragma unroll
            for (int k = 0; k < PPT2; ++k) {
                float d  = sqdist_exact(px[k], py[k], pz[k], cx, cy, cz);
                float nd = fminf(dmin[k], d);
                dmin[k] = nd;
                bool gt = nd > bv;
                bv = gt ? nd : bv;
                bk = gt ? k : bk;
            }
            unsigned gi = (unsigned)(bk * NT + t);
            unsigned long long pk =
                ((unsigned long long)__float_as_uint(bv) << 32) | (unsigned)(~gi);
            pk = wave_max_key(pk);
            if (lane == 63) wkey[par][w] = pk;
            __syncthreads();
            const unsigned widx = reduce8_widx(wkey[par], lane);
            // winner coords from LDS (~120 cyc, beats L2)
            cx = cb1[widx * 3 + 0];
            cy = cb1[widx * 3 + 1];
            cz = cb1[widx * 3 + 2];
        }
    }
    __syncthreads();
    // flush centers2 LDS -> global
#pragma unroll 1
    for (int i = t; i < (M2_ * 3) / 4; i += NT)
        ((float4*)(centers2 + (size_t)b * M2_ * 3))[i] = ((const float4*)cb2)[i];
}

// ---------------- exact kNN (top-32 smallest sq-dist, tie -> smaller index) ----------------
// radix-select over float bit patterns (all d >= 0 -> monotone in uint bits)
template<int N, int M>
__global__ void __launch_bounds__(64)
knn_kernel(const float* __restrict__ pts, const float* __restrict__ centers,
           int* __restrict__ nidx) {
    constexpr int K = KNN_;
    constexpr int CAP = 224;
    const int bm = blockIdx.x;
    const int b = bm / M;
    const int lane = threadIdx.x;
    const float* P = pts + (size_t)b * N * 3;
    const float* c = centers + (size_t)bm * 3;
    const float cx = c[0], cy = c[1], cz = c[2];
    int* out = nidx + (size_t)bm * K;

    __shared__ int hist[2048];
    __shared__ unsigned int eqk[CAP];
    __shared__ int eqi[CAP];
    __shared__ int cnt_less, cnt_eq;

    unsigned int prefix = 0; int pbits = 0;
    unsigned int Tlo = 0; unsigned long long Thi = 0x100000000ull;
    int L = 0, target = K, Cbin = N;

    for (int round = 0; round < 3; ++round) {
        const int bits  = (round < 2) ? 11 : 10;
        const int nbins = 1 << bits;
        const int shift = 32 - pbits - bits;
        for (int i = lane; i < nbins; i += 64) hist[i] = 0;
        __syncthreads();
        for (int j = lane; j < N; j += 64) {
            float d = sqdist_exact(P[j * 3], P[j * 3 + 1], P[j * 3 + 2], cx, cy, cz);
            unsigned int key = __float_as_uint(d);
            if (key >= Tlo && (unsigned long long)key < Thi)
                atomicAdd(&hist[(key >> shift) & (nbins - 1)], 1);
        }
        __syncthreads();
        const int per = nbins / 64;
        int s = 0;
        for (int i = 0; i < per; ++i) s += hist[lane * per + i];
        int cum = s;
        for (int off = 1; off < 64; off <<= 1) {
            int o = __shfl_up(cum, off);
            if (lane >= off) cum += o;
        }
        int cumex = cum - s;
        bool has = (cumex < target) && (cum >= target);
        unsigned long long ball = __ballot(has);
        int src = __ffsll(ball) - 1;
        int binsel = 0, Ladd = 0, bincnt = 0;
        if (lane == src) {
            int acc = cumex;
            for (int i = 0; i < per; ++i) {
                int h = hist[lane * per + i];
                if (acc + h >= target) { binsel = lane * per + i; Ladd = acc; bincnt = h; break; }
                acc += h;
            }
        }
        binsel = __shfl(binsel, src);
        Ladd   = __shfl(Ladd, src);
        bincnt = __shfl(bincnt, src);
        L += Ladd;
        target -= Ladd;
        prefix = (prefix << bits) | (unsigned int)binsel;
        pbits += bits;
        Tlo = prefix << (32 - pbits);
        Thi = ((unsigned long long)prefix + 1ull) << (32 - pbits);
        Cbin = bincnt;
        __syncthreads();
        if (Cbin <= CAP) break;
    }

    if (lane == 0) { cnt_less = 0; cnt_eq = 0; }
    __syncthreads();

    if (Cbin <= CAP) {
        for (int j = lane; j < N; j += 64) {
            float d = sqdist_exact(P[j * 3], P[j * 3 + 1], P[j * 3 + 2], cx, cy, cz);
            unsigned int key = __float_as_uint(d);
            if (key < Tlo) {
                int p = atomicAdd(&cnt_less, 1);
                out[p] = j;
            } else if ((unsigned long long)key < Thi) {
                int p = atomicAdd(&cnt_eq, 1);
                eqk[p] = key; eqi[p] = j;
            }
        }
        __syncthreads();
        const int E = cnt_eq;
        for (int e = lane; e < E; e += 64) {
            unsigned int ke = eqk[e]; int ie = eqi[e];
            int rank = 0;
            for (int f = 0; f < E; ++f) {
                unsigned int kf = eqk[f]; int jf = eqi[f];
                rank += (kf < ke || (kf == ke && jf < ie)) ? 1 : 0;
            }
            if (rank < target) out[L + rank] = ie;
        }
    } else {
        // pbits==32: giant tie class at exact key Tlo -> take smallest indices in order
        int cnt = 0;
        for (int jb = 0; jb < N; jb += 64) {
            int j = jb + lane;
            float d = sqdist_exact(P[j * 3], P[j * 3 + 1], P[j * 3 + 2], cx, cy, cz);
            unsigned int key = __float_as_uint(d);
            if (key < Tlo) {
                int p = atomicAdd(&cnt_less, 1);
                out[p] = j;
            }
            bool eq = (key == Tlo);
            unsigned long long mb = __ballot(eq);
            int below = __popcll(mb & ((1ull << lane) - 1ull));
            if (eq && (cnt + below) < target) out[L + cnt + below] = j;
            cnt += (int)__popcll(mb);
        }
    }
}

// ---------------- grouped 2-layer MLP + max-pool over 32 neighbors ----------------
// g stored as [nf(FD) | rel(3) | pad], Wa rows remapped accordingly.
template<int NPTS, int FD, int CO, int M>
__global__ void __launch_bounds__(CO)
group_mlp_kernel(const float* __restrict__ pts, const float* __restrict__ feats,
                 const float* __restrict__ centers, const int* __restrict__ nidx,
                 const float* __restrict__ Wa, const float* __restrict__ ba,
                 const float* __restrict__ Wb, const float* __restrict__ bb,
                 float* __restrict__ outf) {
    constexpr int KN = KNN_;
    constexpr int GS = FD + 4;
    const int bm = blockIdx.x;
    const int b = bm / M;
    const int t = threadIdx.x;
    __shared__ float g[KN][GS];
    __shared__ float h1[KN][CO];
    const int* nb = nidx + (size_t)bm * KN;
    const float* cen = centers + (size_t)bm * 3;
    const float cx = cen[0], cy = cen[1], cz = cen[2];
    {
        constexpr int PARTS = CO / KN;        // 4 (L1) or 8 (L2)
        constexpr int CHUNK = FD / PARTS;     // 16
        const int kk = t / PARTS;
        const int q  = t % PARTS;
        const int j  = nb[kk];
        const float* f = feats + ((size_t)b * NPTS + j) * FD + q * CHUNK;
        float* gr = &g[kk][q * CHUNK];
#pragma unroll
        for (int u = 0; u < CHUNK / 4; ++u)
            *(float4*)(gr + 4 * u) = *(const float4*)(f + 4 * u);
        if (q == 0) {
            const float* p = pts + ((size_t)b * NPTS + j) * 3;
            g[kk][FD + 0] = __fsub_rn(p[0], cx);
            g[kk][FD + 1] = __fsub_rn(p[1], cy);
            g[kk][FD + 2] = __fsub_rn(p[2], cz);
            g[kk][FD + 3] = 0.f;
        }
    }
    __syncthreads();
    const int o = t;
    float acc[KN];
#pragma unroll
    for (int k = 0; k < KN; ++k) acc[k] = ba[o];
    for (int s4 = 0; s4 < FD / 4; ++s4) {   // nf part: stored s -> Wa row s+3
        const float w0 = Wa[(4 * s4 + 3) * CO + o];
        const float w1 = Wa[(4 * s4 + 4) * CO + o];
        const float w2 = Wa[(4 * s4 + 5) * CO + o];
        const float w3 = Wa[(4 * s4 + 6) * CO + o];
#pragma unroll
        for (int k = 0; k < KN; ++k) {
            float4 gv = *(const float4*)&g[k][4 * s4];
            acc[k] = __fmaf_rn(gv.x, w0, acc[k]);
            acc[k] = __fmaf_rn(gv.y, w1, acc[k]);
            acc[k] = __fmaf_rn(gv.z, w2, acc[k]);
            acc[k] = __fmaf_rn(gv.w, w3, acc[k]);
        }
    }
    {
        const float w0 = Wa[0 * CO + o];
        const float w1 = Wa[1 * CO + o];
        const float w2 = Wa[2 * CO + o];
#pragma unroll
        for (int k = 0; k < KN; ++k) {
            float4 gv = *(const float4*)&g[k][FD];
            acc[k] = __fmaf_rn(gv.x, w0, acc[k]);
            acc[k] = __fmaf_rn(gv.y, w1, acc[k]);
            acc[k] = __fmaf_rn(gv.z, w2, acc[k]);
        }
    }
#pragma unroll
    for (int k = 0; k < KN; ++k) h1[k][o] = fmaxf(acc[k], 0.f);
    __syncthreads();
#pragma unroll
    for (int k = 0; k < KN; ++k) acc[k] = bb[o];
    for (int s4 = 0; s4 < CO / 4; ++s4) {
        const float w0 = Wb[(4 * s4 + 0) * CO + o];
        const float w1 = Wb[(4 * s4 + 1) * CO + o];
        const float w2 = Wb[(4 * s4 + 2) * CO + o];
        const float w3 = Wb[(4 * s4 + 3) * CO + o];
#pragma unroll
        for (int k = 0; k < KN; ++k) {
            float4 hv = *(const float4*)&h1[k][4 * s4];
            acc[k] = __fmaf_rn(hv.x, w0, acc[k]);
            acc[k] = __fmaf_rn(hv.y, w1, acc[k]);
            acc[k] = __fmaf_rn(hv.z, w2, acc[k]);
            acc[k] = __fmaf_rn(hv.w, w3, acc[k]);
        }
    }
    float mx = 0.f;
#pragma unroll
    for (int k = 0; k < KN; ++k) mx = fmaxf(mx, fmaxf(acc[k], 0.f));
    outf[(size_t)bm * CO + o] = mx;
}

// ---------------- global head: [max|mean] -> relu(g@Wd1+b) -> @Wd2+b ----------------
__global__ void __launch_bounds__(256)
head_kernel(const float* __restrict__ feats2,
            const float* __restrict__ Wd1, const float* __restrict__ bd1,
            const float* __restrict__ Wd2, const float* __restrict__ bd2,
            float* __restrict__ outp) {
    const int b = blockIdx.x, t = threadIdx.x;
    __shared__ float gsh[2 * C2_];
    __shared__ float hsh[512];
    const float* F = feats2 + (size_t)b * M2_ * C2_;
    float mx = -1e30f, sm = 0.f;
    for (int r = 0; r < M2_; ++r) {
        float v = F[r * C2_ + t];
        mx = fmaxf(mx, v);
        sm += v;
    }
    gsh[t] = mx;
    gsh[C2_ + t] = sm * (1.0f / (float)M2_);
    __syncthreads();
#pragma unroll
    for (int oo = 0; oo < 2; ++oo) {
        const int o = t + oo * 256;
        float acc = bd1[o];
        for (int i = 0; i < 512; ++i)
            acc = __fmaf_rn(gsh[i], Wd1[i * 512 + o], acc);
        hsh[o] = fmaxf(acc, 0.f);
    }
    __syncthreads();
    float acc = bd2[t];
    for (int i = 0; i < 512; ++i)
        acc = __fmaf_rn(hsh[i], Wd2[i * 256 + t], acc);
    outp[b * 256 + t] = acc;
}

extern "C" void kernel_launch(void* const* d_in, const int* in_sizes, int n_in,
                              void* d_out, int out_size, void* d_ws, size_t ws_size,
                              hipStream_t stream) {
    const float* xyz = (const float*)d_in[0];
    const float* Wp  = (const float*)d_in[1];
    const float* bp  = (const float*)d_in[2];
    const float* W1a = (const float*)d_in[3];
    const float* b1a = (const float*)d_in[4];
    const float* W1b = (const float*)d_in[5];
    const float* b1b = (const float*)d_in[6];
    const float* W2a = (const float*)d_in[7];
    const float* b2a = (const float*)d_in[8];
    const float* W2b = (const float*)d_in[9];
    const float* b2b = (const float*)d_in[10];
    const float* Wd1 = (const float*)d_in[11];
    const float* bd1 = (const float*)d_in[12];
    const float* Wd2 = (const float*)d_in[13];
    const float* bd2 = (const float*)d_in[14];
    float* out = (float*)d_out;

    char* ws = (char*)d_ws;
    size_t off = 0;
    auto alloc = [&](size_t bytes) { void* p = ws + off; off += (bytes + 255) & ~(size_t)255; return p; };
    float* feats0   = (float*)alloc((size_t)B_ * N1_ * PROJ_ * 4);
    float* centers1 = (float*)alloc((size_t)B_ * M1_ * 3 * 4);
    int*   nidx1    = (int*)  alloc((size_t)B_ * M1_ * KNN_ * 4);
    float* feats1   = (float*)alloc((size_t)B_ * M1_ * C1_ * 4);
    float* centers2 = (float*)alloc((size_t)B_ * M2_ * 3 * 4);
    int*   nidx2    = (int*)  alloc((size_t)B_ * M2_ * KNN_ * 4);
    float* feats2   = (float*)alloc((size_t)B_ * M2_ * C2_ * 4);
    (void)in_sizes; (void)n_in; (void)out_size; (void)ws_size;

    proj_kernel<<<dim3(B_ * N1_ * PROJ_ / 256), dim3(256), 0, stream>>>(xyz, Wp, bp, feats0);
    fps_fused_kernel<<<dim3(B_), dim3(512), 0, stream>>>(xyz, centers1, centers2);
    knn_kernel<N1_, M1_><<<dim3(B_ * M1_), dim3(64), 0, stream>>>(xyz, centers1, nidx1);
    group_mlp_kernel<N1_, PROJ_, C1_, M1_><<<dim3(B_ * M1_), dim3(C1_), 0, stream>>>(
        xyz, feats0, centers1, nidx1, W1a, b1a, W1b, b1b, feats1);
    knn_kernel<M1_, M2_><<<dim3(B_ * M2_), dim3(64), 0, stream>>>(centers1, centers2, nidx2);
    group_mlp_kernel<M1_, C1_, C2_, M2_><<<dim3(B_ * M2_), dim3(C2_), 0, stream>>>(
        centers1, feats1, centers2, nidx2, W2a, b2a, W2b, b2b, feats2);
    head_kernel<<<dim3(B_), dim3(256), 0, stream>>>(feats2, Wd1, bd1, Wd2, bd2, out);
}

// Round 6
// 4211.587 us; speedup vs baseline: 2.4464x; 1.0299x over previous
//
#include <hip/hip_runtime.h>

#define B_    4
#define N1_   16384
#define M1_   2048
#define M2_   512
#define KNN_  32
#define PROJ_ 64
#define C1_   128
#define C2_   256

__device__ __forceinline__ float sqdist_exact(float px, float py, float pz,
                                              float cx, float cy, float cz) {
    // Must match numpy: ((dx*dx + dy*dy) + dz*dz), no FMA contraction.
    float dx = __fsub_rn(px, cx);
    float dy = __fsub_rn(py, cy);
    float dz = __fsub_rn(pz, cz);
    return __fadd_rn(__fadd_rn(__fmul_rn(dx, dx), __fmul_rn(dy, dy)), __fmul_rn(dz, dz));
}

// ---------------- projection: feats0[b,n,c] = xyz[b,n,:] @ Wp + bp ----------------
__global__ void __launch_bounds__(256)
proj_kernel(const float* __restrict__ xyz, const float* __restrict__ Wp,
            const float* __restrict__ bp, float* __restrict__ feats0) {
    int tid = blockIdx.x * 256 + threadIdx.x;
    int c = tid & (PROJ_ - 1);
    int pn = tid >> 6;
    if (pn >= B_ * N1_) return;
    const float* p = xyz + (size_t)pn * 3;
    float acc = p[0] * Wp[0 * PROJ_ + c];
    acc = __fmaf_rn(p[1], Wp[1 * PROJ_ + c], acc);
    acc = __fmaf_rn(p[2], Wp[2 * PROJ_ + c], acc);
    feats0[tid] = acc + bp[c];
}

// ---------------- farthest point sampling (both levels fused) ----------------
// Serial-latency-bound; 1 CU per batch (r4: cross-CU exchange = net loss).
// key = (f32bits(dmin) << 32) | ~gidx : u64 max == max value, tie -> min index
// (exactly jnp.argmax first-occurrence semantics; d >= 0 so f32 bits monotone).
// Round-10:
//  - phase A in packed fp32 via NATIVE float2 ops (v_pk_add/mul_f32; NOT asm --
//    r3 showed asm constraints poison regalloc). `#pragma clang fp contract(off)`
//    keeps mul/add unfused -> per-element IEEE == scalar ((dx*dx+dy*dy)+dz*dz).
//  - amdgpu_num_vgpr(224): r1/r2/r5 all showed VGPR_Count < live state (88 vs
//    ~150) -> allocator AGPR-homes loop state, costing ~280 accvgpr moves/iter.
//    Explicit arch budget (224*2 waves <= 512-reg pool) removes its reason.
//  - DPP wave scan, lean 8-key reduce, LDS centers staging, fused stage 2
//    carried over (all proven bit-exact through r5).
typedef float v2f __attribute__((ext_vector_type(2)));

template<int CTRL, int RM>
__device__ __forceinline__ unsigned long long dpp_umax64(unsigned long long pk) {
    unsigned lo = (unsigned)__builtin_amdgcn_update_dpp(
        0, (int)(unsigned)pk, CTRL, RM, 0xf, true);
    unsigned hi = (unsigned)__builtin_amdgcn_update_dpp(
        0, (int)(unsigned)(pk >> 32), CTRL, RM, 0xf, true);
    unsigned long long o = ((unsigned long long)hi << 32) | (unsigned long long)lo;
    return (o > pk) ? o : pk;
}

__device__ __forceinline__ unsigned long long wave_max_key(unsigned long long pk) {
    pk = dpp_umax64<0x111, 0xf>(pk);   // row_shr:1
    pk = dpp_umax64<0x112, 0xf>(pk);   // row_shr:2
    pk = dpp_umax64<0x114, 0xf>(pk);   // row_shr:4
    pk = dpp_umax64<0x118, 0xf>(pk);   // row_shr:8
    pk = dpp_umax64<0x142, 0xa>(pk);   // row_bcast15 -> rows 1,3
    pk = dpp_umax64<0x143, 0xc>(pk);   // row_bcast31 -> rows 2,3
    return pk;                          // lane 63 holds the wave max
}

// Lean 8-key reduce: lane reads wkey[lane&7] (one ds_read_b64/wave, grouped,
// conflict-free), 3-step DPP scan puts max(keys 0..7) in lane 7; readlane ->
// uniform SGPR. Bit-exact: u64 max is associative/commutative.
__device__ __forceinline__ unsigned reduce8_widx(const unsigned long long* wk,
                                                 int lane) {
    unsigned long long k8 = wk[lane & 7];
    k8 = dpp_umax64<0x111, 0xf>(k8);
    k8 = dpp_umax64<0x112, 0xf>(k8);
    k8 = dpp_umax64<0x114, 0xf>(k8);
    unsigned lo = (unsigned)__builtin_amdgcn_readlane((int)(unsigned)k8, 7);
    return ~lo;   // uniform winner index
}

__global__ __attribute__((amdgpu_flat_work_group_size(512, 512)))
__attribute__((amdgpu_waves_per_eu(2, 2)))
__attribute__((amdgpu_num_vgpr(224)))
void fps_fused_kernel(const float* __restrict__ pts,
                      float* __restrict__ centers1,
                      float* __restrict__ centers2) {
#pragma clang fp contract(off)
    constexpr int NT = 512;
    constexpr int NW = NT / 64;          // 8
    constexpr int NP1 = (N1_ / NT) / 2;  // 16 point-pairs (stage 1)
    constexpr int NP2 = (M1_ / NT) / 2;  // 2 point-pairs  (stage 2)
    const int b = blockIdx.x;
    const int t = threadIdx.x;
    const int w = t >> 6;
    const int lane = t & 63;
    const float* P = pts + (size_t)b * N1_ * 3;

    __shared__ alignas(16) unsigned long long wkey[2][NW];
    __shared__ alignas(16) float cb1[M1_ * 3];   // 24 KB, centers1 staging
    __shared__ alignas(16) float cb2[M2_ * 3];   //  6 KB, centers2 staging

    // ================= stage 1: FPS over global pts (N1 -> M1) =================
    {
        v2f px2[NP1], py2[NP1], pz2[NP1];
        float dmin[2 * NP1];
#pragma unroll
        for (int p = 0; p < NP1; ++p) {
            const int j0 = (2 * p) * NT + t;
            const int j1 = j0 + NT;
            px2[p] = (v2f){P[j0 * 3 + 0], P[j1 * 3 + 0]};
            py2[p] = (v2f){P[j0 * 3 + 1], P[j1 * 3 + 1]};
            pz2[p] = (v2f){P[j0 * 3 + 2], P[j1 * 3 + 2]};
            dmin[2 * p] = 1e10f; dmin[2 * p + 1] = 1e10f;
        }
        // anti-remat insurance on the load-derived values only
#pragma unroll
        for (int p = 0; p < NP1; ++p)
            asm volatile("" : "+v"(px2[p]), "+v"(py2[p]), "+v"(pz2[p]));

        float cx = P[0], cy = P[1], cz = P[2];

        for (int m = 0; m < M1_; ++m) {
            if (t == 0) {
                cb1[m * 3 + 0] = cx; cb1[m * 3 + 1] = cy; cb1[m * 3 + 2] = cz;
            }
            if (m == M1_ - 1) break;
            const int par = m & 1;
            // ---- A: packed sqdist (2 pts/inst); scalar dmin/argmax tracking.
            // Scan order 2p then 2p+1 with strict > == first-occurrence argmax.
            const v2f c2x = {cx, cx}, c2y = {cy, cy}, c2z = {cz, cz};
            float bv = -1.0f; int bk = 0;
#pragma unroll
            for (int p = 0; p < NP1; ++p) {
                v2f dx = px2[p] - c2x;
                v2f dy = py2[p] - c2y;
                v2f dz = pz2[p] - c2z;
                v2f d2 = (dx * dx + dy * dy) + dz * dz;   // contract(off): exact
                float nd0 = fminf(dmin[2 * p],     d2.x);
                float nd1 = fminf(dmin[2 * p + 1], d2.y);
                dmin[2 * p]     = nd0;
                dmin[2 * p + 1] = nd1;
                bool g0 = nd0 > bv; bv = g0 ? nd0 : bv; bk = g0 ? 2 * p     : bk;
                bool g1 = nd1 > bv; bv = g1 ? nd1 : bv; bk = g1 ? 2 * p + 1 : bk;
            }
            // ---- B: pack (value, ~gidx); wave max via DPP scan
            unsigned gi = (unsigned)(bk * NT + t);
            unsigned long long pk =
                ((unsigned long long)__float_as_uint(bv) << 32) | (unsigned)(~gi);
            pk = wave_max_key(pk);
            if (lane == 63) wkey[par][w] = pk;
            __syncthreads();               // the ONLY barrier per iter
            // ---- C: lean reduce -> uniform winner index
            const unsigned widx = reduce8_widx(wkey[par], lane);
            // ---- D: winner coords via scalar (uniform) load — L2-resident
            const float* cp = P + (size_t)widx * 3;
            cx = cp[0]; cy = cp[1]; cz = cp[2];
        }
    }
    __syncthreads();
    // flush centers1 LDS -> global, coalesced float4
#pragma unroll 1
    for (int i = t; i < (M1_ * 3) / 4; i += NT)
        ((float4*)(centers1 + (size_t)b * M1_ * 3))[i] = ((const float4*)cb1)[i];

    // ================= stage 2: FPS over cb1 in LDS (M1 -> M2) =================
    {
        v2f px2[NP2], py2[NP2], pz2[NP2];
        float dmin[2 * NP2];
#pragma unroll
        for (int p = 0; p < NP2; ++p) {
            const int j0 = (2 * p) * NT + t;
            const int j1 = j0 + NT;
            px2[p] = (v2f){cb1[j0 * 3 + 0], cb1[j1 * 3 + 0]};
            py2[p] = (v2f){cb1[j0 * 3 + 1], cb1[j1 * 3 + 1]};
            pz2[p] = (v2f){cb1[j0 * 3 + 2], cb1[j1 * 3 + 2]};
            dmin[2 * p] = 1e10f; dmin[2 * p + 1] = 1e10f;
        }
#pragma unroll
        for (int p = 0; p < NP2; ++p)
            asm volatile("" : "+v"(px2[p]), "+v"(py2[p]), "+v"(pz2[p]));

        float cx = cb1[0], cy = cb1[1], cz = cb1[2];

        for (int m = 0; m < M2_; ++m) {
            if (t == 0) {
                cb2[m * 3 + 0] = cx; cb2[m * 3 + 1] = cy; cb2[m * 3 + 2] = cz;
            }
            if (m == M2_ - 1) break;
            const int par = m & 1;
            const v2f c2x = {cx, cx}, c2y = {cy, cy}, c2z = {cz, cz};
            float bv = -1.0f; int bk = 0;
#pragma unroll
            for (int p = 0; p < NP2; ++p) {
                v2f dx = px2[p] - c2x;
                v2f dy = py2[p] - c2y;
                v2f dz = pz2[p] - c2z;
                v2f d2 = (dx * dx + dy * dy) + dz * dz;
                float nd0 = fminf(dmin[2 * p],     d2.x);
                float nd1 = fminf(dmin[2 * p + 1], d2.y);
                dmin[2 * p]     = nd0;
                dmin[2 * p + 1] = nd1;
                bool g0 = nd0 > bv; bv = g0 ? nd0 : bv; bk = g0 ? 2 * p     : bk;
                bool g1 = nd1 > bv; bv = g1 ? nd1 : bv; bk = g1 ? 2 * p + 1 : bk;
            }
            unsigned gi = (unsigned)(bk * NT + t);
            unsigned long long pk =
                ((unsigned long long)__float_as_uint(bv) << 32) | (unsigned)(~gi);
            pk = wave_max_key(pk);
            if (lane == 63) wkey[par][w] = pk;
            __syncthreads();
            const unsigned widx = reduce8_widx(wkey[par], lane);
            // winner coords from LDS (uniform broadcast read)
            cx = cb1[widx * 3 + 0];
            cy = cb1[widx * 3 + 1];
            cz = cb1[widx * 3 + 2];
        }
    }
    __syncthreads();
    // flush centers2 LDS -> global
#pragma unroll 1
    for (int i = t; i < (M2_ * 3) / 4; i += NT)
        ((float4*)(centers2 + (size_t)b * M2_ * 3))[i] = ((const float4*)cb2)[i];
}

// ---------------- exact kNN (top-32 smallest sq-dist, tie -> smaller index) ----------------
// radix-select over float bit patterns (all d >= 0 -> monotone in uint bits)
template<int N, int M>
__global__ void __launch_bounds__(64)
knn_kernel(const float* __restrict__ pts, const float* __restrict__ centers,
           int* __restrict__ nidx) {
    constexpr int K = KNN_;
    constexpr int CAP = 224;
    const int bm = blockIdx.x;
    const int b = bm / M;
    const int lane = threadIdx.x;
    const float* P = pts + (size_t)b * N * 3;
    const float* c = centers + (size_t)bm * 3;
    const float cx = c[0], cy = c[1], cz = c[2];
    int* out = nidx + (size_t)bm * K;

    __shared__ int hist[2048];
    __shared__ unsigned int eqk[CAP];
    __shared__ int eqi[CAP];
    __shared__ int cnt_less, cnt_eq;

    unsigned int prefix = 0; int pbits = 0;
    unsigned int Tlo = 0; unsigned long long Thi = 0x100000000ull;
    int L = 0, target = K, Cbin = N;

    for (int round = 0; round < 3; ++round) {
        const int bits  = (round < 2) ? 11 : 10;
        const int nbins = 1 << bits;
        const int shift = 32 - pbits - bits;
        for (int i = lane; i < nbins; i += 64) hist[i] = 0;
        __syncthreads();
        for (int j = lane; j < N; j += 64) {
            float d = sqdist_exact(P[j * 3], P[j * 3 + 1], P[j * 3 + 2], cx, cy, cz);
            unsigned int key = __float_as_uint(d);
            if (key >= Tlo && (unsigned long long)key < Thi)
                atomicAdd(&hist[(key >> shift) & (nbins - 1)], 1);
        }
        __syncthreads();
        const int per = nbins / 64;
        int s = 0;
        for (int i = 0; i < per; ++i) s += hist[lane * per + i];
        int cum = s;
        for (int off = 1; off < 64; off <<= 1) {
            int o = __shfl_up(cum, off);
            if (lane >= off) cum += o;
        }
        int cumex = cum - s;
        bool has = (cumex < target) && (cum >= target);
        unsigned long long ball = __ballot(has);
        int src = __ffsll(ball) - 1;
        int binsel = 0, Ladd = 0, bincnt = 0;
        if (lane == src) {
            int acc = cumex;
            for (int i = 0; i < per; ++i) {
                int h = hist[lane * per + i];
                if (acc + h >= target) { binsel = lane * per + i; Ladd = acc; bincnt = h; break; }
                acc += h;
            }
        }
        binsel = __shfl(binsel, src);
        Ladd   = __shfl(Ladd, src);
        bincnt = __shfl(bincnt, src);
        L += Ladd;
        target -= Ladd;
        prefix = (prefix << bits) | (unsigned int)binsel;
        pbits += bits;
        Tlo = prefix << (32 - pbits);
        Thi = ((unsigned long long)prefix + 1ull) << (32 - pbits);
        Cbin = bincnt;
        __syncthreads();
        if (Cbin <= CAP) break;
    }

    if (lane == 0) { cnt_less = 0; cnt_eq = 0; }
    __syncthreads();

    if (Cbin <= CAP) {
        for (int j = lane; j < N; j += 64) {
            float d = sqdist_exact(P[j * 3], P[j * 3 + 1], P[j * 3 + 2], cx, cy, cz);
            unsigned int key = __float_as_uint(d);
            if (key < Tlo) {
                int p = atomicAdd(&cnt_less, 1);
                out[p] = j;
            } else if ((unsigned long long)key < Thi) {
                int p = atomicAdd(&cnt_eq, 1);
                eqk[p] = key; eqi[p] = j;
            }
        }
        __syncthreads();
        const int E = cnt_eq;
        for (int e = lane; e < E; e += 64) {
            unsigned int ke = eqk[e]; int ie = eqi[e];
            int rank = 0;
            for (int f = 0; f < E; ++f) {
                unsigned int kf = eqk[f]; int jf = eqi[f];
                rank += (kf < ke || (kf == ke && jf < ie)) ? 1 : 0;
            }
            if (rank < target) out[L + rank] = ie;
        }
    } else {
        // pbits==32: giant tie class at exact key Tlo -> take smallest indices in order
        int cnt = 0;
        for (int jb = 0; jb < N; jb += 64) {
            int j = jb + lane;
            float d = sqdist_exact(P[j * 3], P[j * 3 + 1], P[j * 3 + 2], cx, cy, cz);
            unsigned int key = __float_as_uint(d);
            if (key < Tlo) {
                int p = atomicAdd(&cnt_less, 1);
                out[p] = j;
            }
            bool eq = (key == Tlo);
            unsigned long long mb = __ballot(eq);
            int below = __popcll(mb & ((1ull << lane) - 1ull));
            if (eq && (cnt + below) < target) out[L + cnt + below] = j;
            cnt += (int)__popcll(mb);
        }
    }
}

// ---------------- grouped 2-layer MLP + max-pool over 32 neighbors ----------------
// g stored as [nf(FD) | rel(3) | pad], Wa rows remapped accordingly.
template<int NPTS, int FD, int CO, int M>
__global__ void __launch_bounds__(CO)
group_mlp_kernel(const float* __restrict__ pts, const float* __restrict__ feats,
                 const float* __restrict__ centers, const int* __restrict__ nidx,
                 const float* __restrict__ Wa, const float* __restrict__ ba,
                 const float* __restrict__ Wb, const float* __restrict__ bb,
                 float* __restrict__ outf) {
    constexpr int KN = KNN_;
    constexpr int GS = FD + 4;
    const int bm = blockIdx.x;
    const int b = bm / M;
    const int t = threadIdx.x;
    __shared__ float g[KN][GS];
    __shared__ float h1[KN][CO];
    const int* nb = nidx + (size_t)bm * KN;
    const float* cen = centers + (size_t)bm * 3;
    const float cx = cen[0], cy = cen[1], cz = cen[2];
    {
        constexpr int PARTS = CO / KN;        // 4 (L1) or 8 (L2)
        constexpr int CHUNK = FD / PARTS;     // 16
        const int kk = t / PARTS;
        const int q  = t % PARTS;
        const int j  = nb[kk];
        const float* f = feats + ((size_t)b * NPTS + j) * FD + q * CHUNK;
        float* gr = &g[kk][q * CHUNK];
#pragma unroll
        for (int u = 0; u < CHUNK / 4; ++u)
            *(float4*)(gr + 4 * u) = *(const float4*)(f + 4 * u);
        if (q == 0) {
            const float* p = pts + ((size_t)b * NPTS + j) * 3;
            g[kk][FD + 0] = __fsub_rn(p[0], cx);
            g[kk][FD + 1] = __fsub_rn(p[1], cy);
            g[kk][FD + 2] = __fsub_rn(p[2], cz);
            g[kk][FD + 3] = 0.f;
        }
    }
    __syncthreads();
    const int o = t;
    float acc[KN];
#pragma unroll
    for (int k = 0; k < KN; ++k) acc[k] = ba[o];
    for (int s4 = 0; s4 < FD / 4; ++s4) {   // nf part: stored s -> Wa row s+3
        const float w0 = Wa[(4 * s4 + 3) * CO + o];
        const float w1 = Wa[(4 * s4 + 4) * CO + o];
        const float w2 = Wa[(4 * s4 + 5) * CO + o];
        const float w3 = Wa[(4 * s4 + 6) * CO + o];
#pragma unroll
        for (int k = 0; k < KN; ++k) {
            float4 gv = *(const float4*)&g[k][4 * s4];
            acc[k] = __fmaf_rn(gv.x, w0, acc[k]);
            acc[k] = __fmaf_rn(gv.y, w1, acc[k]);
            acc[k] = __fmaf_rn(gv.z, w2, acc[k]);
            acc[k] = __fmaf_rn(gv.w, w3, acc[k]);
        }
    }
    {
        const float w0 = Wa[0 * CO + o];
        const float w1 = Wa[1 * CO + o];
        const float w2 = Wa[2 * CO + o];
#pragma unroll
        for (int k = 0; k < KN; ++k) {
            float4 gv = *(const float4*)&g[k][FD];
            acc[k] = __fmaf_rn(gv.x, w0, acc[k]);
            acc[k] = __fmaf_rn(gv.y, w1, acc[k]);
            acc[k] = __fmaf_rn(gv.z, w2, acc[k]);
        }
    }
#pragma unroll
    for (int k = 0; k < KN; ++k) h1[k][o] = fmaxf(acc[k], 0.f);
    __syncthreads();
#pragma unroll
    for (int k = 0; k < KN; ++k) acc[k] = bb[o];
    for (int s4 = 0; s4 < CO / 4; ++s4) {
        const float w0 = Wb[(4 * s4 + 0) * CO + o];
        const float w1 = Wb[(4 * s4 + 1) * CO + o];
        const float w2 = Wb[(4 * s4 + 2) * CO + o];
        const float w3 = Wb[(4 * s4 + 3) * CO + o];
#pragma unroll
        for (int k = 0; k < KN; ++k) {
            float4 hv = *(const float4*)&h1[k][4 * s4];
            acc[k] = __fmaf_rn(hv.x, w0, acc[k]);
            acc[k] = __fmaf_rn(hv.y, w1, acc[k]);
            acc[k] = __fmaf_rn(hv.z, w2, acc[k]);
            acc[k] = __fmaf_rn(hv.w, w3, acc[k]);
        }
    }
    float mx = 0.f;
#pragma unroll
    for (int k = 0; k < KN; ++k) mx = fmaxf(mx, fmaxf(acc[k], 0.f));
    outf[(size_t)bm * CO + o] = mx;
}

// ---------------- global head: [max|mean] -> relu(g@Wd1+b) -> @Wd2+b ----------------
__global__ void __launch_bounds__(256)
head_kernel(const float* __restrict__ feats2,
            const float* __restrict__ Wd1, const float* __restrict__ bd1,
            const float* __restrict__ Wd2, const float* __restrict__ bd2,
            float* __restrict__ outp) {
    const int b = blockIdx.x, t = threadIdx.x;
    __shared__ float gsh[2 * C2_];
    __shared__ float hsh[512];
    const float* F = feats2 + (size_t)b * M2_ * C2_;
    float mx = -1e30f, sm = 0.f;
    for (int r = 0; r < M2_; ++r) {
        float v = F[r * C2_ + t];
        mx = fmaxf(mx, v);
        sm += v;
    }
    gsh[t] = mx;
    gsh[C2_ + t] = sm * (1.0f / (float)M2_);
    __syncthreads();
#pragma unroll
    for (int oo = 0; oo < 2; ++oo) {
        const int o = t + oo * 256;
        float acc = bd1[o];
        for (int i = 0; i < 512; ++i)
            acc = __fmaf_rn(gsh[i], Wd1[i * 512 + o], acc);
        hsh[o] = fmaxf(acc, 0.f);
    }
    __syncthreads();
    float acc = bd2[t];
    for (int i = 0; i < 512; ++i)
        acc = __fmaf_rn(hsh[i], Wd2[i * 256 + t], acc);
    outp[b * 256 + t] = acc;
}

extern "C" void kernel_launch(void* const* d_in, const int* in_sizes, int n_in,
                              void* d_out, int out_size, void* d_ws, size_t ws_size,
                              hipStream_t stream) {
    const float* xyz = (const float*)d_in[0];
    const float* Wp  = (const float*)d_in[1];
    const float* bp  = (const float*)d_in[2];
    const float* W1a = (const float*)d_in[3];
    const float* b1a = (const float*)d_in[4];
    const float* W1b = (const float*)d_in[5];
    const float* b1b = (const float*)d_in[6];
    const float* W2a = (const float*)d_in[7];
    const float* b2a = (const float*)d_in[8];
    const float* W2b = (const float*)d_in[9];
    const float* b2b = (const float*)d_in[10];
    const float* Wd1 = (const float*)d_in[11];
    const float* bd1 = (const float*)d_in[12];
    const float* Wd2 = (const float*)d_in[13];
    const float* bd2 = (const float*)d_in[14];
    float* out = (float*)d_out;

    char* ws = (char*)d_ws;
    size_t off = 0;
    auto alloc = [&](size_t bytes) { void* p = ws + off; off += (bytes + 255) & ~(size_t)255; return p; };
    float* feats0   = (float*)alloc((size_t)B_ * N1_ * PROJ_ * 4);
    float* centers1 = (float*)alloc((size_t)B_ * M1_ * 3 * 4);
    int*   nidx1    = (int*)  alloc((size_t)B_ * M1_ * KNN_ * 4);
    float* feats1   = (float*)alloc((size_t)B_ * M1_ * C1_ * 4);
    float* centers2 = (float*)alloc((size_t)B_ * M2_ * 3 * 4);
    int*   nidx2    = (int*)  alloc((size_t)B_ * M2_ * KNN_ * 4);
    float* feats2   = (float*)alloc((size_t)B_ * M2_ * C2_ * 4);
    (void)in_sizes; (void)n_in; (void)out_size; (void)ws_size;

    proj_kernel<<<dim3(B_ * N1_ * PROJ_ / 256), dim3(256), 0, stream>>>(xyz, Wp, bp, feats0);
    fps_fused_kernel<<<dim3(B_), dim3(512), 0, stream>>>(xyz, centers1, centers2);
    knn_kernel<N1_, M1_><<<dim3(B_ * M1_), dim3(64), 0, stream>>>(xyz, centers1, nidx1);
    group_mlp_kernel<N1_, PROJ_, C1_, M1_><<<dim3(B_ * M1_), dim3(C1_), 0, stream>>>(
        xyz, feats0, centers1, nidx1, W1a, b1a, W1b, b1b, feats1);
    knn_kernel<M1_, M2_><<<dim3(B_ * M2_), dim3(64), 0, stream>>>(centers1, centers2, nidx2);
    group_mlp_kernel<M1_, C1_, C2_, M2_><<<dim3(B_ * M2_), dim3(C2_), 0, stream>>>(
        centers1, feats1, centers2, nidx2, W2a, b2a, W2b, b2b, feats2);
    head_kernel<<<dim3(B_), dim3(256), 0, stream>>>(feats2, Wd1, bd1, Wd2, bd2, out);
}

// Round 7
// 4084.793 us; speedup vs baseline: 2.5223x; 1.0310x over previous
//
#include <hip/hip_runtime.h>

#define B_    4
#define N1_   16384
#define M1_   2048
#define M2_   512
#define KNN_  32
#define PROJ_ 64
#define C1_   128
#define C2_   256

__device__ __forceinline__ float sqdist_exact(float px, float py, float pz,
                                              float cx, float cy, float cz) {
    // Must match numpy: ((dx*dx + dy*dy) + dz*dz), no FMA contraction.
    float dx = __fsub_rn(px, cx);
    float dy = __fsub_rn(py, cy);
    float dz = __fsub_rn(pz, cz);
    return __fadd_rn(__fadd_rn(__fmul_rn(dx, dx), __fmul_rn(dy, dy)), __fmul_rn(dz, dz));
}

// ---------------- FPS primitives (proven bit-exact through r6) ----------------
// key = (f32bits(dmin) << 32) | ~gidx : u64 max == max value, tie -> min index
// (exactly jnp.argmax first-occurrence semantics; d >= 0 so f32 bits monotone).
typedef float v2f __attribute__((ext_vector_type(2)));

template<int CTRL, int RM>
__device__ __forceinline__ unsigned long long dpp_umax64(unsigned long long pk) {
    unsigned lo = (unsigned)__builtin_amdgcn_update_dpp(
        0, (int)(unsigned)pk, CTRL, RM, 0xf, true);
    unsigned hi = (unsigned)__builtin_amdgcn_update_dpp(
        0, (int)(unsigned)(pk >> 32), CTRL, RM, 0xf, true);
    unsigned long long o = ((unsigned long long)hi << 32) | (unsigned long long)lo;
    return (o > pk) ? o : pk;
}

__device__ __forceinline__ unsigned long long wave_max_key(unsigned long long pk) {
    pk = dpp_umax64<0x111, 0xf>(pk);   // row_shr:1
    pk = dpp_umax64<0x112, 0xf>(pk);   // row_shr:2
    pk = dpp_umax64<0x114, 0xf>(pk);   // row_shr:4
    pk = dpp_umax64<0x118, 0xf>(pk);   // row_shr:8
    pk = dpp_umax64<0x142, 0xa>(pk);   // row_bcast15 -> rows 1,3
    pk = dpp_umax64<0x143, 0xc>(pk);   // row_bcast31 -> rows 2,3
    return pk;                          // lane 63 holds the wave max
}

// Lean 8-key reduce (NW=8): lane reads wkey[lane&7], 3-step DPP, readlane(7).
__device__ __forceinline__ unsigned reduce8_widx(const unsigned long long* wk,
                                                 int lane) {
    unsigned long long k8 = wk[lane & 7];
    k8 = dpp_umax64<0x111, 0xf>(k8);
    k8 = dpp_umax64<0x112, 0xf>(k8);
    k8 = dpp_umax64<0x114, 0xf>(k8);
    unsigned lo = (unsigned)__builtin_amdgcn_readlane((int)(unsigned)k8, 7);
    return ~lo;   // uniform winner index
}

// Lean 2-key reduce (NW=2): lane reads wkey[lane&1], 1-step DPP, readlane(1).
__device__ __forceinline__ unsigned reduce2_widx(const unsigned long long* wk,
                                                 int lane) {
    unsigned long long k2 = wk[lane & 1];
    k2 = dpp_umax64<0x111, 0xf>(k2);
    unsigned lo = (unsigned)__builtin_amdgcn_readlane((int)(unsigned)k2, 1);
    return ~lo;
}

// ---------------- kernel 1: FPS stage 1 (blocks 0..3) + projection (rest) ----
// Round-11: proj fused as extra blocks — fps blocks dispatch first and own 4
// CUs for ~3 ms; proj floods the other 252 CUs and finishes in ~60 us "free".
// (Correctness is dispatch-order independent: the paths touch disjoint data.)
__global__ __attribute__((amdgpu_flat_work_group_size(512, 512)))
__attribute__((amdgpu_waves_per_eu(2, 2)))
__attribute__((amdgpu_num_vgpr(224)))
void fps1_proj_kernel(const float* __restrict__ xyz,
                      const float* __restrict__ Wp, const float* __restrict__ bp,
                      float* __restrict__ feats0, float* __restrict__ centers1) {
#pragma clang fp contract(off)
    if (blockIdx.x >= B_) {
        // ---- projection path: feats0[b,n,c] = xyz[b,n,:] @ Wp + bp
        int tid = (blockIdx.x - B_) * 512 + threadIdx.x;
        int c = tid & (PROJ_ - 1);
        int pn = tid >> 6;
        const float* p = xyz + (size_t)pn * 3;
        float acc = p[0] * Wp[0 * PROJ_ + c];
        acc = __fmaf_rn(p[1], Wp[1 * PROJ_ + c], acc);
        acc = __fmaf_rn(p[2], Wp[2 * PROJ_ + c], acc);
        feats0[tid] = acc + bp[c];
        return;
    }
    // ---- FPS stage 1 (N1 -> M1), r6 structure verbatim
    constexpr int NT = 512;
    constexpr int NW = NT / 64;          // 8
    constexpr int NP1 = (N1_ / NT) / 2;  // 16 point-pairs
    const int b = blockIdx.x;
    const int t = threadIdx.x;
    const int w = t >> 6;
    const int lane = t & 63;
    const float* P = xyz + (size_t)b * N1_ * 3;
    float* C1 = centers1 + (size_t)b * M1_ * 3;

    __shared__ alignas(16) unsigned long long wkey[2][NW];
    __shared__ alignas(16) float cb1[M1_ * 3];   // 24 KB, centers1 staging

    v2f px2[NP1], py2[NP1], pz2[NP1];
    float dmin[2 * NP1];
#pragma unroll
    for (int p = 0; p < NP1; ++p) {
        const int j0 = (2 * p) * NT + t;
        const int j1 = j0 + NT;
        px2[p] = (v2f){P[j0 * 3 + 0], P[j1 * 3 + 0]};
        py2[p] = (v2f){P[j0 * 3 + 1], P[j1 * 3 + 1]};
        pz2[p] = (v2f){P[j0 * 3 + 2], P[j1 * 3 + 2]};
        dmin[2 * p] = 1e10f; dmin[2 * p + 1] = 1e10f;
    }
#pragma unroll
    for (int p = 0; p < NP1; ++p)
        asm volatile("" : "+v"(px2[p]), "+v"(py2[p]), "+v"(pz2[p]));

    float cx = P[0], cy = P[1], cz = P[2];

    for (int m = 0; m < M1_; ++m) {
        if (t == 0) {
            cb1[m * 3 + 0] = cx; cb1[m * 3 + 1] = cy; cb1[m * 3 + 2] = cz;
        }
        if (m == M1_ - 1) break;
        const int par = m & 1;
        // A: packed sqdist (per-element IEEE exact under contract(off));
        //    scan order 2p then 2p+1 with strict > == first-occurrence argmax.
        const v2f c2x = {cx, cx}, c2y = {cy, cy}, c2z = {cz, cz};
        float bv = -1.0f; int bk = 0;
#pragma unroll
        for (int p = 0; p < NP1; ++p) {
            v2f dx = px2[p] - c2x;
            v2f dy = py2[p] - c2y;
            v2f dz = pz2[p] - c2z;
            v2f d2 = (dx * dx + dy * dy) + dz * dz;
            float nd0 = fminf(dmin[2 * p],     d2.x);
            float nd1 = fminf(dmin[2 * p + 1], d2.y);
            dmin[2 * p]     = nd0;
            dmin[2 * p + 1] = nd1;
            bool g0 = nd0 > bv; bv = g0 ? nd0 : bv; bk = g0 ? 2 * p     : bk;
            bool g1 = nd1 > bv; bv = g1 ? nd1 : bv; bk = g1 ? 2 * p + 1 : bk;
        }
        // B: pack (value, ~gidx); wave max via DPP scan
        unsigned gi = (unsigned)(bk * NT + t);
        unsigned long long pk =
            ((unsigned long long)__float_as_uint(bv) << 32) | (unsigned)(~gi);
        pk = wave_max_key(pk);
        if (lane == 63) wkey[par][w] = pk;
        __syncthreads();               // the ONLY barrier per iter
        // C: lean reduce -> uniform winner index
        const unsigned widx = reduce8_widx(wkey[par], lane);
        // D: winner coords via uniform load — L2-resident
        const float* cp = P + (size_t)widx * 3;
        cx = cp[0]; cy = cp[1]; cz = cp[2];
    }
    __syncthreads();
    // flush centers1 LDS -> global, coalesced float4
#pragma unroll 1
    for (int i = t; i < (M1_ * 3) / 4; i += NT)
        ((float4*)C1)[i] = ((const float4*)cb1)[i];
}

// ---------------- FPS stage 2 body (128 threads; runs inside sa1_kernel) ----
__device__ __forceinline__ void fps2_body(const float* __restrict__ centers1,
                                          float* __restrict__ centers2,
                                          char* arena) {
#pragma clang fp contract(off)
    constexpr int NT = 128;
    constexpr int NW = 2;
    constexpr int NP = (M1_ / NT) / 2;   // 8 point-pairs (16 pts/thread)
    const int b = blockIdx.x;
    const int t = threadIdx.x;
    const int w = t >> 6;
    const int lane = t & 63;
    const float* P = centers1 + (size_t)b * M1_ * 3;
    float* C = centers2 + (size_t)b * M2_ * 3;

    unsigned long long (*wkey)[NW] = (unsigned long long(*)[NW])arena;  // [2][2]
    float* cb2 = (float*)(arena + 64);   // 6 KB staging, 16B-aligned

    v2f px2[NP], py2[NP], pz2[NP];
    float dmin[2 * NP];
#pragma unroll
    for (int p = 0; p < NP; ++p) {
        const int j0 = (2 * p) * NT + t;
        const int j1 = j0 + NT;
        px2[p] = (v2f){P[j0 * 3 + 0], P[j1 * 3 + 0]};
        py2[p] = (v2f){P[j0 * 3 + 1], P[j1 * 3 + 1]};
        pz2[p] = (v2f){P[j0 * 3 + 2], P[j1 * 3 + 2]};
        dmin[2 * p] = 1e10f; dmin[2 * p + 1] = 1e10f;
    }
#pragma unroll
    for (int p = 0; p < NP; ++p)
        asm volatile("" : "+v"(px2[p]), "+v"(py2[p]), "+v"(pz2[p]));

    float cx = P[0], cy = P[1], cz = P[2];

    for (int m = 0; m < M2_; ++m) {
        if (t == 0) {
            cb2[m * 3 + 0] = cx; cb2[m * 3 + 1] = cy; cb2[m * 3 + 2] = cz;
        }
        if (m == M2_ - 1) break;
        const int par = m & 1;
        const v2f c2x = {cx, cx}, c2y = {cy, cy}, c2z = {cz, cz};
        float bv = -1.0f; int bk = 0;
#pragma unroll
        for (int p = 0; p < NP; ++p) {
            v2f dx = px2[p] - c2x;
            v2f dy = py2[p] - c2y;
            v2f dz = pz2[p] - c2z;
            v2f d2 = (dx * dx + dy * dy) + dz * dz;
            float nd0 = fminf(dmin[2 * p],     d2.x);
            float nd1 = fminf(dmin[2 * p + 1], d2.y);
            dmin[2 * p]     = nd0;
            dmin[2 * p + 1] = nd1;
            bool g0 = nd0 > bv; bv = g0 ? nd0 : bv; bk = g0 ? 2 * p     : bk;
            bool g1 = nd1 > bv; bv = g1 ? nd1 : bv; bk = g1 ? 2 * p + 1 : bk;
        }
        unsigned gi = (unsigned)(bk * NT + t);
        unsigned long long pk =
            ((unsigned long long)__float_as_uint(bv) << 32) | (unsigned)(~gi);
        pk = wave_max_key(pk);
        if (lane == 63) wkey[par][w] = pk;
        __syncthreads();
        const unsigned widx = reduce2_widx(wkey[par], lane);
        const float* cp = P + (size_t)widx * 3;   // L2-hot (24 KB)
        cx = cp[0]; cy = cp[1]; cz = cp[2];
    }
    __syncthreads();
#pragma unroll 1
    for (int i = t; i < (M2_ * 3) / 4; i += NT)
        ((float4*)C)[i] = ((const float4*)cb2)[i];
}

// ---------------- grouped 2-layer MLP + max-pool body (arena-based) ----------
// g stored as [nf(FD) | rel(3) | pad], Wa rows remapped accordingly.
template<int NPTS, int FD, int CO, int M>
__device__ __forceinline__ void mlp_body(int bm, char* arena,
                 const float* __restrict__ pts, const float* __restrict__ feats,
                 const float* __restrict__ centers, const int* __restrict__ nidx,
                 const float* __restrict__ Wa, const float* __restrict__ ba,
                 const float* __restrict__ Wb, const float* __restrict__ bb,
                 float* __restrict__ outf) {
    constexpr int KN = KNN_;
    constexpr int GS = FD + 4;
    const int b = bm / M;
    const int t = threadIdx.x;
    float (*g)[GS]  = (float(*)[GS])arena;
    float (*h1)[CO] = (float(*)[CO])(arena + sizeof(float) * KN * GS);
    const int* nb = nidx + (size_t)bm * KN;
    const float* cen = centers + (size_t)bm * 3;
    const float cx = cen[0], cy = cen[1], cz = cen[2];
    {
        constexpr int PARTS = CO / KN;        // 4 (L1) or 8 (L2)
        constexpr int CHUNK = FD / PARTS;     // 16
        const int kk = t / PARTS;
        const int q  = t % PARTS;
        const int j  = nb[kk];
        const float* f = feats + ((size_t)b * NPTS + j) * FD + q * CHUNK;
        float* gr = &g[kk][q * CHUNK];
#pragma unroll
        for (int u = 0; u < CHUNK / 4; ++u)
            *(float4*)(gr + 4 * u) = *(const float4*)(f + 4 * u);
        if (q == 0) {
            const float* p = pts + ((size_t)b * NPTS + j) * 3;
            g[kk][FD + 0] = __fsub_rn(p[0], cx);
            g[kk][FD + 1] = __fsub_rn(p[1], cy);
            g[kk][FD + 2] = __fsub_rn(p[2], cz);
            g[kk][FD + 3] = 0.f;
        }
    }
    __syncthreads();
    const int o = t;
    float acc[KN];
#pragma unroll
    for (int k = 0; k < KN; ++k) acc[k] = ba[o];
    for (int s4 = 0; s4 < FD / 4; ++s4) {   // nf part: stored s -> Wa row s+3
        const float w0 = Wa[(4 * s4 + 3) * CO + o];
        const float w1 = Wa[(4 * s4 + 4) * CO + o];
        const float w2 = Wa[(4 * s4 + 5) * CO + o];
        const float w3 = Wa[(4 * s4 + 6) * CO + o];
#pragma unroll
        for (int k = 0; k < KN; ++k) {
            float4 gv = *(const float4*)&g[k][4 * s4];
            acc[k] = __fmaf_rn(gv.x, w0, acc[k]);
            acc[k] = __fmaf_rn(gv.y, w1, acc[k]);
            acc[k] = __fmaf_rn(gv.z, w2, acc[k]);
            acc[k] = __fmaf_rn(gv.w, w3, acc[k]);
        }
    }
    {
        const float w0 = Wa[0 * CO + o];
        const float w1 = Wa[1 * CO + o];
        const float w2 = Wa[2 * CO + o];
#pragma unroll
        for (int k = 0; k < KN; ++k) {
            float4 gv = *(const float4*)&g[k][FD];
            acc[k] = __fmaf_rn(gv.x, w0, acc[k]);
            acc[k] = __fmaf_rn(gv.y, w1, acc[k]);
            acc[k] = __fmaf_rn(gv.z, w2, acc[k]);
        }
    }
#pragma unroll
    for (int k = 0; k < KN; ++k) h1[k][o] = fmaxf(acc[k], 0.f);
    __syncthreads();
#pragma unroll
    for (int k = 0; k < KN; ++k) acc[k] = bb[o];
    for (int s4 = 0; s4 < CO / 4; ++s4) {
        const float w0 = Wb[(4 * s4 + 0) * CO + o];
        const float w1 = Wb[(4 * s4 + 1) * CO + o];
        const float w2 = Wb[(4 * s4 + 2) * CO + o];
        const float w3 = Wb[(4 * s4 + 3) * CO + o];
#pragma unroll
        for (int k = 0; k < KN; ++k) {
            float4 hv = *(const float4*)&h1[k][4 * s4];
            acc[k] = __fmaf_rn(hv.x, w0, acc[k]);
            acc[k] = __fmaf_rn(hv.y, w1, acc[k]);
            acc[k] = __fmaf_rn(hv.z, w2, acc[k]);
            acc[k] = __fmaf_rn(hv.w, w3, acc[k]);
        }
    }
    float mx = 0.f;
#pragma unroll
    for (int k = 0; k < KN; ++k) mx = fmaxf(mx, fmaxf(acc[k], 0.f));
    outf[(size_t)bm * CO + o] = mx;
}

// ---------------- kernel 3: mlp level-1 (blocks 4..) + FPS stage 2 (0..3) ----
// fps2 blocks dispatch first, run ~220 us on 4 CUs while 8192 mlp blocks use
// the rest -> stage 2 leaves the critical path. knn2 (next kernel) consumes
// centers2 across the kernel boundary, so no intra-kernel dependency exists.
__global__ void __launch_bounds__(C1_)
sa1_kernel(const float* __restrict__ xyz, const float* __restrict__ feats0,
           const float* __restrict__ centers1, const int* __restrict__ nidx1,
           const float* __restrict__ W1a, const float* __restrict__ b1a,
           const float* __restrict__ W1b, const float* __restrict__ b1b,
           float* __restrict__ feats1, float* __restrict__ centers2) {
    constexpr size_t MLP_BYTES =
        sizeof(float) * (KNN_ * (PROJ_ + 4) + KNN_ * C1_);   // 25088
    __shared__ alignas(16) char arena[MLP_BYTES];            // fps2 uses 6.3 KB
    if (blockIdx.x < B_) {
        fps2_body(centers1, centers2, arena);
        return;
    }
    mlp_body<N1_, PROJ_, C1_, M1_>(blockIdx.x - B_, arena, xyz, feats0,
                                   centers1, nidx1, W1a, b1a, W1b, b1b, feats1);
}

// ---------------- standalone mlp kernel (level 2) ----------------
template<int NPTS, int FD, int CO, int M>
__global__ void __launch_bounds__(CO)
group_mlp_kernel(const float* __restrict__ pts, const float* __restrict__ feats,
                 const float* __restrict__ centers, const int* __restrict__ nidx,
                 const float* __restrict__ Wa, const float* __restrict__ ba,
                 const float* __restrict__ Wb, const float* __restrict__ bb,
                 float* __restrict__ outf) {
    constexpr size_t BYTES = sizeof(float) * (KNN_ * (FD + 4) + KNN_ * CO);
    __shared__ alignas(16) char arena[BYTES];
    mlp_body<NPTS, FD, CO, M>(blockIdx.x, arena, pts, feats, centers, nidx,
                              Wa, ba, Wb, bb, outf);
}

// ---------------- exact kNN (top-32 smallest sq-dist, tie -> smaller index) ----------------
// radix-select over float bit patterns (all d >= 0 -> monotone in uint bits)
template<int N, int M>
__global__ void __launch_bounds__(64)
knn_kernel(const float* __restrict__ pts, const float* __restrict__ centers,
           int* __restrict__ nidx) {
    constexpr int K = KNN_;
    constexpr int CAP = 224;
    const int bm = blockIdx.x;
    const int b = bm / M;
    const int lane = threadIdx.x;
    const float* P = pts + (size_t)b * N * 3;
    const float* c = centers + (size_t)bm * 3;
    const float cx = c[0], cy = c[1], cz = c[2];
    int* out = nidx + (size_t)bm * K;

    __shared__ int hist[2048];
    __shared__ unsigned int eqk[CAP];
    __shared__ int eqi[CAP];
    __shared__ int cnt_less, cnt_eq;

    unsigned int prefix = 0; int pbits = 0;
    unsigned int Tlo = 0; unsigned long long Thi = 0x100000000ull;
    int L = 0, target = K, Cbin = N;

    for (int round = 0; round < 3; ++round) {
        const int bits  = (round < 2) ? 11 : 10;
        const int nbins = 1 << bits;
        const int shift = 32 - pbits - bits;
        for (int i = lane; i < nbins; i += 64) hist[i] = 0;
        __syncthreads();
        for (int j = lane; j < N; j += 64) {
            float d = sqdist_exact(P[j * 3], P[j * 3 + 1], P[j * 3 + 2], cx, cy, cz);
            unsigned int key = __float_as_uint(d);
            if (key >= Tlo && (unsigned long long)key < Thi)
                atomicAdd(&hist[(key >> shift) & (nbins - 1)], 1);
        }
        __syncthreads();
        const int per = nbins / 64;
        int s = 0;
        for (int i = 0; i < per; ++i) s += hist[lane * per + i];
        int cum = s;
        for (int off = 1; off < 64; off <<= 1) {
            int o = __shfl_up(cum, off);
            if (lane >= off) cum += o;
        }
        int cumex = cum - s;
        bool has = (cumex < target) && (cum >= target);
        unsigned long long ball = __ballot(has);
        int src = __ffsll(ball) - 1;
        int binsel = 0, Ladd = 0, bincnt = 0;
        if (lane == src) {
            int acc = cumex;
            for (int i = 0; i < per; ++i) {
                int h = hist[lane * per + i];
                if (acc + h >= target) { binsel = lane * per + i; Ladd = acc; bincnt = h; break; }
                acc += h;
            }
        }
        binsel = __shfl(binsel, src);
        Ladd   = __shfl(Ladd, src);
        bincnt = __shfl(bincnt, src);
        L += Ladd;
        target -= Ladd;
        prefix = (prefix << bits) | (unsigned int)binsel;
        pbits += bits;
        Tlo = prefix << (32 - pbits);
        Thi = ((unsigned long long)prefix + 1ull) << (32 - pbits);
        Cbin = bincnt;
        __syncthreads();
        if (Cbin <= CAP) break;
    }

    if (lane == 0) { cnt_less = 0; cnt_eq = 0; }
    __syncthreads();

    if (Cbin <= CAP) {
        for (int j = lane; j < N; j += 64) {
            float d = sqdist_exact(P[j * 3], P[j * 3 + 1], P[j * 3 + 2], cx, cy, cz);
            unsigned int key = __float_as_uint(d);
            if (key < Tlo) {
                int p = atomicAdd(&cnt_less, 1);
                out[p] = j;
            } else if ((unsigned long long)key < Thi) {
                int p = atomicAdd(&cnt_eq, 1);
                eqk[p] = key; eqi[p] = j;
            }
        }
        __syncthreads();
        const int E = cnt_eq;
        for (int e = lane; e < E; e += 64) {
            unsigned int ke = eqk[e]; int ie = eqi[e];
            int rank = 0;
            for (int f = 0; f < E; ++f) {
                unsigned int kf = eqk[f]; int jf = eqi[f];
                rank += (kf < ke || (kf == ke && jf < ie)) ? 1 : 0;
            }
            if (rank < target) out[L + rank] = ie;
        }
    } else {
        // pbits==32: giant tie class at exact key Tlo -> take smallest indices in order
        int cnt = 0;
        for (int jb = 0; jb < N; jb += 64) {
            int j = jb + lane;
            float d = sqdist_exact(P[j * 3], P[j * 3 + 1], P[j * 3 + 2], cx, cy, cz);
            unsigned int key = __float_as_uint(d);
            if (key < Tlo) {
                int p = atomicAdd(&cnt_less, 1);
                out[p] = j;
            }
            bool eq = (key == Tlo);
            unsigned long long mb = __ballot(eq);
            int below = __popcll(mb & ((1ull << lane) - 1ull));
            if (eq && (cnt + below) < target) out[L + cnt + below] = j;
            cnt += (int)__popcll(mb);
        }
    }
}

// ---------------- global head: [max|mean] -> relu(g@Wd1+b) -> @Wd2+b ----------------
__global__ void __launch_bounds__(256)
head_kernel(const float* __restrict__ feats2,
            const float* __restrict__ Wd1, const float* __restrict__ bd1,
            const float* __restrict__ Wd2, const float* __restrict__ bd2,
            float* __restrict__ outp) {
    const int b = blockIdx.x, t = threadIdx.x;
    __shared__ float gsh[2 * C2_];
    __shared__ float hsh[512];
    const float* F = feats2 + (size_t)b * M2_ * C2_;
    float mx = -1e30f, sm = 0.f;
    for (int r = 0; r < M2_; ++r) {
        float v = F[r * C2_ + t];
        mx = fmaxf(mx, v);
        sm += v;
    }
    gsh[t] = mx;
    gsh[C2_ + t] = sm * (1.0f / (float)M2_);
    __syncthreads();
#pragma unroll
    for (int oo = 0; oo < 2; ++oo) {
        const int o = t + oo * 256;
        float acc = bd1[o];
        for (int i = 0; i < 512; ++i)
            acc = __fmaf_rn(gsh[i], Wd1[i * 512 + o], acc);
        hsh[o] = fmaxf(acc, 0.f);
    }
    __syncthreads();
    float acc = bd2[t];
    for (int i = 0; i < 512; ++i)
        acc = __fmaf_rn(hsh[i], Wd2[i * 256 + t], acc);
    outp[b * 256 + t] = acc;
}

extern "C" void kernel_launch(void* const* d_in, const int* in_sizes, int n_in,
                              void* d_out, int out_size, void* d_ws, size_t ws_size,
                              hipStream_t stream) {
    const float* xyz = (const float*)d_in[0];
    const float* Wp  = (const float*)d_in[1];
    const float* bp  = (const float*)d_in[2];
    const float* W1a = (const float*)d_in[3];
    const float* b1a = (const float*)d_in[4];
    const float* W1b = (const float*)d_in[5];
    const float* b1b = (const float*)d_in[6];
    const float* W2a = (const float*)d_in[7];
    const float* b2a = (const float*)d_in[8];
    const float* W2b = (const float*)d_in[9];
    const float* b2b = (const float*)d_in[10];
    const float* Wd1 = (const float*)d_in[11];
    const float* bd1 = (const float*)d_in[12];
    const float* Wd2 = (const float*)d_in[13];
    const float* bd2 = (const float*)d_in[14];
    float* out = (float*)d_out;

    char* ws = (char*)d_ws;
    size_t off = 0;
    auto alloc = [&](size_t bytes) { void* p = ws + off; off += (bytes + 255) & ~(size_t)255; return p; };
    float* feats0   = (float*)alloc((size_t)B_ * N1_ * PROJ_ * 4);
    float* centers1 = (float*)alloc((size_t)B_ * M1_ * 3 * 4);
    int*   nidx1    = (int*)  alloc((size_t)B_ * M1_ * KNN_ * 4);
    float* feats1   = (float*)alloc((size_t)B_ * M1_ * C1_ * 4);
    float* centers2 = (float*)alloc((size_t)B_ * M2_ * 3 * 4);
    int*   nidx2    = (int*)  alloc((size_t)B_ * M2_ * KNN_ * 4);
    float* feats2   = (float*)alloc((size_t)B_ * M2_ * C2_ * 4);
    (void)in_sizes; (void)n_in; (void)out_size; (void)ws_size;

    // 1: FPS stage 1 (blocks 0..3) + projection (8192 blocks)
    fps1_proj_kernel<<<dim3(B_ + (B_ * N1_ * PROJ_) / 512), dim3(512), 0, stream>>>(
        xyz, Wp, bp, feats0, centers1);
    // 2: kNN level 1
    knn_kernel<N1_, M1_><<<dim3(B_ * M1_), dim3(64), 0, stream>>>(xyz, centers1, nidx1);
    // 3: MLP level 1 (blocks 4..) + FPS stage 2 (blocks 0..3)
    sa1_kernel<<<dim3(B_ + B_ * M1_), dim3(C1_), 0, stream>>>(
        xyz, feats0, centers1, nidx1, W1a, b1a, W1b, b1b, feats1, centers2);
    // 4: kNN level 2
    knn_kernel<M1_, M2_><<<dim3(B_ * M2_), dim3(64), 0, stream>>>(centers1, centers2, nidx2);
    // 5: MLP level 2
    group_mlp_kernel<M1_, C1_, C2_, M2_><<<dim3(B_ * M2_), dim3(C2_), 0, stream>>>(
        centers1, feats1, centers2, nidx2, W2a, b2a, W2b, b2b, feats2);
    // 6: head
    head_kernel<<<dim3(B_), dim3(256), 0, stream>>>(feats2, Wd1, bd1, Wd2, bd2, out);
}

// Round 8
// 3857.616 us; speedup vs baseline: 2.6708x; 1.0589x over previous
//
#include <hip/hip_runtime.h>

#define B_    4
#define N1_   16384
#define M1_   2048
#define M2_   512
#define KNN_  32
#define PROJ_ 64
#define C1_   128
#define C2_   256
#define PROJ_BLKS_ ((B_ * N1_ * PROJ_) / 512)   // 8192
#define KNN_BLKS_  ((M1_ / 64) * (B_ * 64))     // 8192 (chunk-major order)

__device__ __forceinline__ float sqdist_exact(float px, float py, float pz,
                                              float cx, float cy, float cz) {
    // Must match numpy: ((dx*dx + dy*dy) + dz*dz), no FMA contraction.
    float dx = __fsub_rn(px, cx);
    float dy = __fsub_rn(py, cy);
    float dz = __fsub_rn(pz, cz);
    return __fadd_rn(__fadd_rn(__fmul_rn(dx, dx), __fmul_rn(dy, dy)), __fmul_rn(dz, dz));
}

// ---------------- FPS primitives (proven bit-exact through r7) ----------------
// key = (f32bits(dmin) << 32) | ~gidx : u64 max == max value, tie -> min index
// (exactly jnp.argmax first-occurrence semantics; d >= 0 so f32 bits monotone).
typedef float v2f __attribute__((ext_vector_type(2)));

template<int CTRL, int RM>
__device__ __forceinline__ unsigned long long dpp_umax64(unsigned long long pk) {
    unsigned lo = (unsigned)__builtin_amdgcn_update_dpp(
        0, (int)(unsigned)pk, CTRL, RM, 0xf, true);
    unsigned hi = (unsigned)__builtin_amdgcn_update_dpp(
        0, (int)(unsigned)(pk >> 32), CTRL, RM, 0xf, true);
    unsigned long long o = ((unsigned long long)hi << 32) | (unsigned long long)lo;
    return (o > pk) ? o : pk;
}

__device__ __forceinline__ unsigned long long wave_max_key(unsigned long long pk) {
    pk = dpp_umax64<0x111, 0xf>(pk);   // row_shr:1
    pk = dpp_umax64<0x112, 0xf>(pk);   // row_shr:2
    pk = dpp_umax64<0x114, 0xf>(pk);   // row_shr:4
    pk = dpp_umax64<0x118, 0xf>(pk);   // row_shr:8
    pk = dpp_umax64<0x142, 0xa>(pk);   // row_bcast15 -> rows 1,3
    pk = dpp_umax64<0x143, 0xc>(pk);   // row_bcast31 -> rows 2,3
    return pk;                          // lane 63 holds the wave max
}

__device__ __forceinline__ unsigned reduce8_widx(const unsigned long long* wk,
                                                 int lane) {
    unsigned long long k8 = wk[lane & 7];
    k8 = dpp_umax64<0x111, 0xf>(k8);
    k8 = dpp_umax64<0x112, 0xf>(k8);
    k8 = dpp_umax64<0x114, 0xf>(k8);
    unsigned lo = (unsigned)__builtin_amdgcn_readlane((int)(unsigned)k8, 7);
    return ~lo;   // uniform winner index
}

__device__ __forceinline__ unsigned reduce2_widx(const unsigned long long* wk,
                                                 int lane) {
    unsigned long long k2 = wk[lane & 1];
    k2 = dpp_umax64<0x111, 0xf>(k2);
    unsigned lo = (unsigned)__builtin_amdgcn_readlane((int)(unsigned)k2, 1);
    return ~lo;
}

// ---------------- 512-thread exact kNN body (for the megakernel) -------------
// Same radix-select semantics as the 64-thread version (proven through r7):
// top-32 smallest sq-dist; output order within the "less" class is arbitrary
// (consumer max-pool is permutation-invariant); eq-class cut is exact with
// tie -> smaller index. Giant-tie fallback (never hit on real data) runs on
// wave 0 only, preserving the sequential-ballot logic.
template<int N>
__device__ void knn_body512(const float* __restrict__ P,
                            float cx, float cy, float cz,
                            int* __restrict__ out, char* arena) {
    constexpr int K = KNN_;
    constexpr int CAP = 224;
    const int t = threadIdx.x;
    const int lane = t & 63;
    const int w = t >> 6;

    int*      hist = (int*)arena;                       // 2048 ints = 8 KB
    unsigned* eqk  = (unsigned*)(arena + 8192);         // 224
    int*      eqi  = (int*)(arena + 8192 + 896);        // 224
    int*      wsum = (int*)(arena + 8192 + 1792);       // 8
    int*      ctrl = (int*)(arena + 8192 + 1824);       // [0]=less [1]=eq [2]=binsel [3]=Ladd [4]=bincnt

    unsigned prefix = 0; int pbits = 0;
    unsigned Tlo = 0; unsigned long long Thi = 0x100000000ull;
    int L = 0, target = K, Cbin = N;

    for (int round = 0; round < 3; ++round) {
        const int bits  = (round < 2) ? 11 : 10;
        const int nbins = 1 << bits;
        const int shift = 32 - pbits - bits;
        for (int i = t; i < nbins; i += 512) hist[i] = 0;
        __syncthreads();
        for (int j = t; j < N; j += 512) {
            float d = sqdist_exact(P[j * 3], P[j * 3 + 1], P[j * 3 + 2], cx, cy, cz);
            unsigned key = __float_as_uint(d);
            if (key >= Tlo && (unsigned long long)key < Thi)
                atomicAdd(&hist[(key >> shift) & (nbins - 1)], 1);
        }
        __syncthreads();
        const int per = nbins / 512;           // 4 / 4 / 2
        int s = 0;
        for (int i = 0; i < per; ++i) s += hist[t * per + i];
        int cum = s;
        for (int off = 1; off < 64; off <<= 1) {
            int o = __shfl_up(cum, off);
            if (lane >= off) cum += o;
        }
        if (lane == 63) wsum[w] = cum;
        __syncthreads();
        int wpre = 0;
        for (int i = 0; i < w; ++i) wpre += wsum[i];
        cum += wpre;
        const int cumex = cum - s;
        if ((cumex < target) && (cum >= target)) {   // exactly one thread
            int acc = cumex;
            for (int i = 0; i < per; ++i) {
                int h = hist[t * per + i];
                if (acc + h >= target) { ctrl[2] = t * per + i; ctrl[3] = acc; ctrl[4] = h; break; }
                acc += h;
            }
        }
        __syncthreads();
        const int binsel = ctrl[2];
        const int Ladd   = ctrl[3];
        const int bincnt = ctrl[4];
        L += Ladd;
        target -= Ladd;
        prefix = (prefix << bits) | (unsigned)binsel;
        pbits += bits;
        Tlo = prefix << (32 - pbits);
        Thi = ((unsigned long long)prefix + 1ull) << (32 - pbits);
        Cbin = bincnt;
        __syncthreads();
        if (Cbin <= CAP) break;
    }

    if (t == 0) { ctrl[0] = 0; ctrl[1] = 0; }
    __syncthreads();

    if (Cbin <= CAP) {
        for (int j = t; j < N; j += 512) {
            float d = sqdist_exact(P[j * 3], P[j * 3 + 1], P[j * 3 + 2], cx, cy, cz);
            unsigned key = __float_as_uint(d);
            if (key < Tlo) {
                int p = atomicAdd(&ctrl[0], 1);
                out[p] = j;
            } else if ((unsigned long long)key < Thi) {
                int p = atomicAdd(&ctrl[1], 1);
                eqk[p] = key; eqi[p] = j;
            }
        }
        __syncthreads();
        const int E = ctrl[1];
        for (int e = t; e < E; e += 512) {
            unsigned ke = eqk[e]; int ie = eqi[e];
            int rank = 0;
            for (int f = 0; f < E; ++f) {
                unsigned kf = eqk[f]; int jf = eqi[f];
                rank += (kf < ke || (kf == ke && jf < ie)) ? 1 : 0;
            }
            if (rank < target) out[L + rank] = ie;
        }
    } else {
        // pbits==32 giant tie class: wave 0 only, sequential-ballot (rare path)
        if (t < 64) {
            int cnt = 0;
            for (int jb = 0; jb < N; jb += 64) {
                int j = jb + lane;
                float d = sqdist_exact(P[j * 3], P[j * 3 + 1], P[j * 3 + 2], cx, cy, cz);
                unsigned key = __float_as_uint(d);
                if (key < Tlo) {
                    int p = atomicAdd(&ctrl[0], 1);
                    out[p] = j;
                }
                bool eq = (key == Tlo);
                unsigned long long mb = __ballot(eq);
                int below = __popcll(mb & ((1ull << lane) - 1ull));
                if (eq && (cnt + below) < target) out[L + cnt + below] = j;
                cnt += (int)__popcll(mb);
            }
        }
    }
}

// ---------------- megakernel: fps1 (0..3) + proj + chunk-pipelined knn1 -----
// Round-12: fps publishes 64-center chunks (stores + barrier vmcnt-drain +
// agent-release flag -> L2 writeback makes chunk LLC-visible). knn blocks are
// grid-ordered chunk-major, poll prog[b] t0-only (relaxed atomic + s_sleep,
// no cache invalidation), read their center via relaxed agent atomics.
// v255 clobber forces VGPR_Count=256 -> 2 waves/SIMD -> exactly one 512-thread
// block per CU: no knn block can co-reside with an fps block and steal issue;
// side effect: 0 AGPRs available, all fps state must live in arch VGPRs.
// Deadlock-free: producers are grid blocks 0..3, dispatched first.
__global__ __attribute__((amdgpu_flat_work_group_size(512, 512)))
__attribute__((amdgpu_waves_per_eu(2, 2)))
void mega1_kernel(const float* __restrict__ xyz,
                  const float* __restrict__ Wp, const float* __restrict__ bp,
                  float* __restrict__ feats0, float* __restrict__ centers1,
                  int* __restrict__ nidx1, unsigned* __restrict__ prog) {
#pragma clang fp contract(off)
    __shared__ alignas(16) char arena[24832];
    asm volatile("" ::: "v255");           // force 256-VGPR allocation (see above)
    const int bid = blockIdx.x;
    const int t = threadIdx.x;

    if (bid >= B_ + PROJ_BLKS_) {
        // ================= kNN path (chunk-major order) =================
        const int k = bid - (B_ + PROJ_BLKS_);
        const int c = k >> 8;              // chunk 0..31
        const int b = (k >> 6) & 3;        // batch
        const int m = c * 64 + (k & 63);   // center index
        if (t == 0) {
            while (__hip_atomic_load(&prog[b * 16], __ATOMIC_RELAXED,
                                     __HIP_MEMORY_SCOPE_AGENT) <= (unsigned)c)
                __builtin_amdgcn_s_sleep(16);
        }
        __syncthreads();
        const unsigned* cw = (const unsigned*)(centers1 + ((size_t)b * M1_ + m) * 3);
        float cx = __uint_as_float(__hip_atomic_load(cw + 0, __ATOMIC_RELAXED, __HIP_MEMORY_SCOPE_AGENT));
        float cy = __uint_as_float(__hip_atomic_load(cw + 1, __ATOMIC_RELAXED, __HIP_MEMORY_SCOPE_AGENT));
        float cz = __uint_as_float(__hip_atomic_load(cw + 2, __ATOMIC_RELAXED, __HIP_MEMORY_SCOPE_AGENT));
        knn_body512<N1_>(xyz + (size_t)b * N1_ * 3, cx, cy, cz,
                         nidx1 + ((size_t)b * M1_ + m) * KNN_, arena);
        return;
    }
    if (bid >= B_) {
        // ================= projection path =================
        int tid = (bid - B_) * 512 + t;
        int cc = tid & (PROJ_ - 1);
        int pn = tid >> 6;
        const float* p = xyz + (size_t)pn * 3;
        float acc = p[0] * Wp[0 * PROJ_ + cc];
        acc = __fmaf_rn(p[1], Wp[1 * PROJ_ + cc], acc);
        acc = __fmaf_rn(p[2], Wp[2 * PROJ_ + cc], acc);
        feats0[tid] = acc + bp[cc];
        return;
    }
    // ================= FPS stage 1 path (r7 structure + chunk publish) ======
    constexpr int NT = 512;
    constexpr int NW = NT / 64;          // 8
    constexpr int NP1 = (N1_ / NT) / 2;  // 16 point-pairs
    const int b = bid;
    const int w = t >> 6;
    const int lane = t & 63;
    const float* P = xyz + (size_t)b * N1_ * 3;
    float* C1 = centers1 + (size_t)b * M1_ * 3;

    unsigned long long (*wkey)[NW] = (unsigned long long(*)[NW])arena;  // [2][8]
    float* cb1 = (float*)(arena + 128);                                 // 24 KB

    v2f px2[NP1], py2[NP1], pz2[NP1];
    float dmin[2 * NP1];
#pragma unroll
    for (int p = 0; p < NP1; ++p) {
        const int j0 = (2 * p) * NT + t;
        const int j1 = j0 + NT;
        px2[p] = (v2f){P[j0 * 3 + 0], P[j1 * 3 + 0]};
        py2[p] = (v2f){P[j0 * 3 + 1], P[j1 * 3 + 1]};
        pz2[p] = (v2f){P[j0 * 3 + 2], P[j1 * 3 + 2]};
        dmin[2 * p] = 1e10f; dmin[2 * p + 1] = 1e10f;
    }
#pragma unroll
    for (int p = 0; p < NP1; ++p)
        asm volatile("" : "+v"(px2[p]), "+v"(py2[p]), "+v"(pz2[p]));

    float cx = P[0], cy = P[1], cz = P[2];

    for (int m = 0; m < M1_; ++m) {
        if (t == 0) {
            cb1[m * 3 + 0] = cx; cb1[m * 3 + 1] = cy; cb1[m * 3 + 2] = cz;
        }
        if ((m & 63) == 63) {
            // publish chunk c = m>>6 : LDS->global copy, drain, release flag
            __syncthreads();
            const int c = m >> 6;
            if (t < 48)
                ((float4*)C1)[c * 48 + t] = ((const float4*)cb1)[c * 48 + t];
            __syncthreads();               // vmcnt(0) drain: stores complete
            if (t == 0)
                __hip_atomic_store(&prog[b * 16], (unsigned)(c + 1),
                                   __ATOMIC_RELEASE, __HIP_MEMORY_SCOPE_AGENT);
        }
        if (m == M1_ - 1) break;
        const int par = m & 1;
        // A: packed sqdist (per-element IEEE exact under contract(off))
        const v2f c2x = {cx, cx}, c2y = {cy, cy}, c2z = {cz, cz};
        float bv = -1.0f; int bk = 0;
#pragma unroll
        for (int p = 0; p < NP1; ++p) {
            v2f dx = px2[p] - c2x;
            v2f dy = py2[p] - c2y;
            v2f dz = pz2[p] - c2z;
            v2f d2 = (dx * dx + dy * dy) + dz * dz;
            float nd0 = fminf(dmin[2 * p],     d2.x);
            float nd1 = fminf(dmin[2 * p + 1], d2.y);
            dmin[2 * p]     = nd0;
            dmin[2 * p + 1] = nd1;
            bool g0 = nd0 > bv; bv = g0 ? nd0 : bv; bk = g0 ? 2 * p     : bk;
            bool g1 = nd1 > bv; bv = g1 ? nd1 : bv; bk = g1 ? 2 * p + 1 : bk;
        }
        // B: pack (value, ~gidx); wave max via DPP scan
        unsigned gi = (unsigned)(bk * NT + t);
        unsigned long long pk =
            ((unsigned long long)__float_as_uint(bv) << 32) | (unsigned)(~gi);
        pk = wave_max_key(pk);
        if (lane == 63) wkey[par][w] = pk;
        __syncthreads();
        // C: lean reduce -> uniform winner index
        const unsigned widx = reduce8_widx(wkey[par], lane);
        // D: winner coords via uniform load — L2-resident
        const float* cp = P + (size_t)widx * 3;
        cx = cp[0]; cy = cp[1]; cz = cp[2];
    }
}

// ---------------- FPS stage 2 body (128 threads; runs inside sa1_kernel) ----
__device__ __forceinline__ void fps2_body(const float* __restrict__ centers1,
                                          float* __restrict__ centers2,
                                          char* arena) {
#pragma clang fp contract(off)
    constexpr int NT = 128;
    constexpr int NW = 2;
    constexpr int NP = (M1_ / NT) / 2;   // 8 point-pairs
    const int b = blockIdx.x;
    const int t = threadIdx.x;
    const int w = t >> 6;
    const int lane = t & 63;
    const float* P = centers1 + (size_t)b * M1_ * 3;
    float* C = centers2 + (size_t)b * M2_ * 3;

    unsigned long long (*wkey)[NW] = (unsigned long long(*)[NW])arena;  // [2][2]
    float* cb2 = (float*)(arena + 64);

    v2f px2[NP], py2[NP], pz2[NP];
    float dmin[2 * NP];
#pragma unroll
    for (int p = 0; p < NP; ++p) {
        const int j0 = (2 * p) * NT + t;
        const int j1 = j0 + NT;
        px2[p] = (v2f){P[j0 * 3 + 0], P[j1 * 3 + 0]};
        py2[p] = (v2f){P[j0 * 3 + 1], P[j1 * 3 + 1]};
        pz2[p] = (v2f){P[j0 * 3 + 2], P[j1 * 3 + 2]};
        dmin[2 * p] = 1e10f; dmin[2 * p + 1] = 1e10f;
    }
#pragma unroll
    for (int p = 0; p < NP; ++p)
        asm volatile("" : "+v"(px2[p]), "+v"(py2[p]), "+v"(pz2[p]));

    float cx = P[0], cy = P[1], cz = P[2];

    for (int m = 0; m < M2_; ++m) {
        if (t == 0) {
            cb2[m * 3 + 0] = cx; cb2[m * 3 + 1] = cy; cb2[m * 3 + 2] = cz;
        }
        if (m == M2_ - 1) break;
        const int par = m & 1;
        const v2f c2x = {cx, cx}, c2y = {cy, cy}, c2z = {cz, cz};
        float bv = -1.0f; int bk = 0;
#pragma unroll
        for (int p = 0; p < NP; ++p) {
            v2f dx = px2[p] - c2x;
            v2f dy = py2[p] - c2y;
            v2f dz = pz2[p] - c2z;
            v2f d2 = (dx * dx + dy * dy) + dz * dz;
            float nd0 = fminf(dmin[2 * p],     d2.x);
            float nd1 = fminf(dmin[2 * p + 1], d2.y);
            dmin[2 * p]     = nd0;
            dmin[2 * p + 1] = nd1;
            bool g0 = nd0 > bv; bv = g0 ? nd0 : bv; bk = g0 ? 2 * p     : bk;
            bool g1 = nd1 > bv; bv = g1 ? nd1 : bv; bk = g1 ? 2 * p + 1 : bk;
        }
        unsigned gi = (unsigned)(bk * NT + t);
        unsigned long long pk =
            ((unsigned long long)__float_as_uint(bv) << 32) | (unsigned)(~gi);
        pk = wave_max_key(pk);
        if (lane == 63) wkey[par][w] = pk;
        __syncthreads();
        const unsigned widx = reduce2_widx(wkey[par], lane);
        const float* cp = P + (size_t)widx * 3;
        cx = cp[0]; cy = cp[1]; cz = cp[2];
    }
    __syncthreads();
#pragma unroll 1
    for (int i = t; i < (M2_ * 3) / 4; i += NT)
        ((float4*)C)[i] = ((const float4*)cb2)[i];
}

// ---------------- grouped 2-layer MLP + max-pool body (arena-based) ----------
template<int NPTS, int FD, int CO, int M>
__device__ __forceinline__ void mlp_body(int bm, char* arena,
                 const float* __restrict__ pts, const float* __restrict__ feats,
                 const float* __restrict__ centers, const int* __restrict__ nidx,
                 const float* __restrict__ Wa, const float* __restrict__ ba,
                 const float* __restrict__ Wb, const float* __restrict__ bb,
                 float* __restrict__ outf) {
    constexpr int KN = KNN_;
    constexpr int GS = FD + 4;
    const int b = bm / M;
    const int t = threadIdx.x;
    float (*g)[GS]  = (float(*)[GS])arena;
    float (*h1)[CO] = (float(*)[CO])(arena + sizeof(float) * KN * GS);
    const int* nb = nidx + (size_t)bm * KN;
    const float* cen = centers + (size_t)bm * 3;
    const float cx = cen[0], cy = cen[1], cz = cen[2];
    {
        constexpr int PARTS = CO / KN;
        constexpr int CHUNK = FD / PARTS;
        const int kk = t / PARTS;
        const int q  = t % PARTS;
        const int j  = nb[kk];
        const float* f = feats + ((size_t)b * NPTS + j) * FD + q * CHUNK;
        float* gr = &g[kk][q * CHUNK];
#pragma unroll
        for (int u = 0; u < CHUNK / 4; ++u)
            *(float4*)(gr + 4 * u) = *(const float4*)(f + 4 * u);
        if (q == 0) {
            const float* p = pts + ((size_t)b * NPTS + j) * 3;
            g[kk][FD + 0] = __fsub_rn(p[0], cx);
            g[kk][FD + 1] = __fsub_rn(p[1], cy);
            g[kk][FD + 2] = __fsub_rn(p[2], cz);
            g[kk][FD + 3] = 0.f;
        }
    }
    __syncthreads();
    const int o = t;
    float acc[KN];
#pragma unroll
    for (int k = 0; k < KN; ++k) acc[k] = ba[o];
    for (int s4 = 0; s4 < FD / 4; ++s4) {
        const float w0 = Wa[(4 * s4 + 3) * CO + o];
        const float w1 = Wa[(4 * s4 + 4) * CO + o];
        const float w2 = Wa[(4 * s4 + 5) * CO + o];
        const float w3 = Wa[(4 * s4 + 6) * CO + o];
#pragma unroll
        for (int k = 0; k < KN; ++k) {
            float4 gv = *(const float4*)&g[k][4 * s4];
            acc[k] = __fmaf_rn(gv.x, w0, acc[k]);
            acc[k] = __fmaf_rn(gv.y, w1, acc[k]);
            acc[k] = __fmaf_rn(gv.z, w2, acc[k]);
            acc[k] = __fmaf_rn(gv.w, w3, acc[k]);
        }
    }
    {
        const float w0 = Wa[0 * CO + o];
        const float w1 = Wa[1 * CO + o];
        const float w2 = Wa[2 * CO + o];
#pragma unroll
        for (int k = 0; k < KN; ++k) {
            float4 gv = *(const float4*)&g[k][FD];
            acc[k] = __fmaf_rn(gv.x, w0, acc[k]);
            acc[k] = __fmaf_rn(gv.y, w1, acc[k]);
            acc[k] = __fmaf_rn(gv.z, w2, acc[k]);
        }
    }
#pragma unroll
    for (int k = 0; k < KN; ++k) h1[k][o] = fmaxf(acc[k], 0.f);
    __syncthreads();
#pragma unroll
    for (int k = 0; k < KN; ++k) acc[k] = bb[o];
    for (int s4 = 0; s4 < CO / 4; ++s4) {
        const float w0 = Wb[(4 * s4 + 0) * CO + o];
        const float w1 = Wb[(4 * s4 + 1) * CO + o];
        const float w2 = Wb[(4 * s4 + 2) * CO + o];
        const float w3 = Wb[(4 * s4 + 3) * CO + o];
#pragma unroll
        for (int k = 0; k < KN; ++k) {
            float4 hv = *(const float4*)&h1[k][4 * s4];
            acc[k] = __fmaf_rn(hv.x, w0, acc[k]);
            acc[k] = __fmaf_rn(hv.y, w1, acc[k]);
            acc[k] = __fmaf_rn(hv.z, w2, acc[k]);
            acc[k] = __fmaf_rn(hv.w, w3, acc[k]);
        }
    }
    float mx = 0.f;
#pragma unroll
    for (int k = 0; k < KN; ++k) mx = fmaxf(mx, fmaxf(acc[k], 0.f));
    outf[(size_t)bm * CO + o] = mx;
}

// ---------------- kernel: mlp level-1 (blocks 4..) + FPS stage 2 (0..3) -----
__global__ void __launch_bounds__(C1_)
sa1_kernel(const float* __restrict__ xyz, const float* __restrict__ feats0,
           const float* __restrict__ centers1, const int* __restrict__ nidx1,
           const float* __restrict__ W1a, const float* __restrict__ b1a,
           const float* __restrict__ W1b, const float* __restrict__ b1b,
           float* __restrict__ feats1, float* __restrict__ centers2) {
    constexpr size_t MLP_BYTES =
        sizeof(float) * (KNN_ * (PROJ_ + 4) + KNN_ * C1_);   // 25088
    __shared__ alignas(16) char arena[MLP_BYTES];
    if (blockIdx.x < B_) {
        fps2_body(centers1, centers2, arena);
        return;
    }
    mlp_body<N1_, PROJ_, C1_, M1_>(blockIdx.x - B_, arena, xyz, feats0,
                                   centers1, nidx1, W1a, b1a, W1b, b1b, feats1);
}

// ---------------- standalone mlp kernel (level 2) ----------------
template<int NPTS, int FD, int CO, int M>
__global__ void __launch_bounds__(CO)
group_mlp_kernel(const float* __restrict__ pts, const float* __restrict__ feats,
                 const float* __restrict__ centers, const int* __restrict__ nidx,
                 const float* __restrict__ Wa, const float* __restrict__ ba,
                 const float* __restrict__ Wb, const float* __restrict__ bb,
                 float* __restrict__ outf) {
    constexpr size_t BYTES = sizeof(float) * (KNN_ * (FD + 4) + KNN_ * CO);
    __shared__ alignas(16) char arena[BYTES];
    mlp_body<NPTS, FD, CO, M>(blockIdx.x, arena, pts, feats, centers, nidx,
                              Wa, ba, Wb, bb, outf);
}

// ---------------- exact kNN, 64-thread version (knn level 2) ----------------
template<int N, int M>
__global__ void __launch_bounds__(64)
knn_kernel(const float* __restrict__ pts, const float* __restrict__ centers,
           int* __restrict__ nidx) {
    constexpr int K = KNN_;
    constexpr int CAP = 224;
    const int bm = blockIdx.x;
    const int b = bm / M;
    const int lane = threadIdx.x;
    const float* P = pts + (size_t)b * N * 3;
    const float* c = centers + (size_t)bm * 3;
    const float cx = c[0], cy = c[1], cz = c[2];
    int* out = nidx + (size_t)bm * K;

    __shared__ int hist[2048];
    __shared__ unsigned int eqk[CAP];
    __shared__ int eqi[CAP];
    __shared__ int cnt_less, cnt_eq;

    unsigned int prefix = 0; int pbits = 0;
    unsigned int Tlo = 0; unsigned long long Thi = 0x100000000ull;
    int L = 0, target = K, Cbin = N;

    for (int round = 0; round < 3; ++round) {
        const int bits  = (round < 2) ? 11 : 10;
        const int nbins = 1 << bits;
        const int shift = 32 - pbits - bits;
        for (int i = lane; i < nbins; i += 64) hist[i] = 0;
        __syncthreads();
        for (int j = lane; j < N; j += 64) {
            float d = sqdist_exact(P[j * 3], P[j * 3 + 1], P[j * 3 + 2], cx, cy, cz);
            unsigned int key = __float_as_uint(d);
            if (key >= Tlo && (unsigned long long)key < Thi)
                atomicAdd(&hist[(key >> shift) & (nbins - 1)], 1);
        }
        __syncthreads();
        const int per = nbins / 64;
        int s = 0;
        for (int i = 0; i < per; ++i) s += hist[lane * per + i];
        int cum = s;
        for (int off = 1; off < 64; off <<= 1) {
            int o = __shfl_up(cum, off);
            if (lane >= off) cum += o;
        }
        int cumex = cum - s;
        bool has = (cumex < target) && (cum >= target);
        unsigned long long ball = __ballot(has);
        int src = __ffsll(ball) - 1;
        int binsel = 0, Ladd = 0, bincnt = 0;
        if (lane == src) {
            int acc = cumex;
            for (int i = 0; i < per; ++i) {
                int h = hist[lane * per + i];
                if (acc + h >= target) { binsel = lane * per + i; Ladd = acc; bincnt = h; break; }
                acc += h;
            }
        }
        binsel = __shfl(binsel, src);
        Ladd   = __shfl(Ladd, src);
        bincnt = __shfl(bincnt, src);
        L += Ladd;
        target -= Ladd;
        prefix = (prefix << bits) | (unsigned int)binsel;
        pbits += bits;
        Tlo = prefix << (32 - pbits);
        Thi = ((unsigned long long)prefix + 1ull) << (32 - pbits);
        Cbin = bincnt;
        __syncthreads();
        if (Cbin <= CAP) break;
    }

    if (lane == 0) { cnt_less = 0; cnt_eq = 0; }
    __syncthreads();

    if (Cbin <= CAP) {
        for (int j = lane; j < N; j += 64) {
            float d = sqdist_exact(P[j * 3], P[j * 3 + 1], P[j * 3 + 2], cx, cy, cz);
            unsigned int key = __float_as_uint(d);
            if (key < Tlo) {
                int p = atomicAdd(&cnt_less, 1);
                out[p] = j;
            } else if ((unsigned long long)key < Thi) {
                int p = atomicAdd(&cnt_eq, 1);
                eqk[p] = key; eqi[p] = j;
            }
        }
        __syncthreads();
        const int E = cnt_eq;
        for (int e = lane; e < E; e += 64) {
            unsigned int ke = eqk[e]; int ie = eqi[e];
            int rank = 0;
            for (int f = 0; f < E; ++f) {
                unsigned int kf = eqk[f]; int jf = eqi[f];
                rank += (kf < ke || (kf == ke && jf < ie)) ? 1 : 0;
            }
            if (rank < target) out[L + rank] = ie;
        }
    } else {
        int cnt = 0;
        for (int jb = 0; jb < N; jb += 64) {
            int j = jb + lane;
            float d = sqdist_exact(P[j * 3], P[j * 3 + 1], P[j * 3 + 2], cx, cy, cz);
            unsigned int key = __float_as_uint(d);
            if (key < Tlo) {
                int p = atomicAdd(&cnt_less, 1);
                out[p] = j;
            }
            bool eq = (key == Tlo);
            unsigned long long mb = __ballot(eq);
            int below = __popcll(mb & ((1ull << lane) - 1ull));
            if (eq && (cnt + below) < target) out[L + cnt + below] = j;
            cnt += (int)__popcll(mb);
        }
    }
}

// ---------------- global head ----------------
__global__ void __launch_bounds__(256)
head_kernel(const float* __restrict__ feats2,
            const float* __restrict__ Wd1, const float* __restrict__ bd1,
            const float* __restrict__ Wd2, const float* __restrict__ bd2,
            float* __restrict__ outp) {
    const int b = blockIdx.x, t = threadIdx.x;
    __shared__ float gsh[2 * C2_];
    __shared__ float hsh[512];
    const float* F = feats2 + (size_t)b * M2_ * C2_;
    float mx = -1e30f, sm = 0.f;
    for (int r = 0; r < M2_; ++r) {
        float v = F[r * C2_ + t];
        mx = fmaxf(mx, v);
        sm += v;
    }
    gsh[t] = mx;
    gsh[C2_ + t] = sm * (1.0f / (float)M2_);
    __syncthreads();
#pragma unroll
    for (int oo = 0; oo < 2; ++oo) {
        const int o = t + oo * 256;
        float acc = bd1[o];
        for (int i = 0; i < 512; ++i)
            acc = __fmaf_rn(gsh[i], Wd1[i * 512 + o], acc);
        hsh[o] = fmaxf(acc, 0.f);
    }
    __syncthreads();
    float acc = bd2[t];
    for (int i = 0; i < 512; ++i)
        acc = __fmaf_rn(hsh[i], Wd2[i * 256 + t], acc);
    outp[b * 256 + t] = acc;
}

extern "C" void kernel_launch(void* const* d_in, const int* in_sizes, int n_in,
                              void* d_out, int out_size, void* d_ws, size_t ws_size,
                              hipStream_t stream) {
    const float* xyz = (const float*)d_in[0];
    const float* Wp  = (const float*)d_in[1];
    const float* bp  = (const float*)d_in[2];
    const float* W1a = (const float*)d_in[3];
    const float* b1a = (const float*)d_in[4];
    const float* W1b = (const float*)d_in[5];
    const float* b1b = (const float*)d_in[6];
    const float* W2a = (const float*)d_in[7];
    const float* b2a = (const float*)d_in[8];
    const float* W2b = (const float*)d_in[9];
    const float* b2b = (const float*)d_in[10];
    const float* Wd1 = (const float*)d_in[11];
    const float* bd1 = (const float*)d_in[12];
    const float* Wd2 = (const float*)d_in[13];
    const float* bd2 = (const float*)d_in[14];
    float* out = (float*)d_out;

    char* ws = (char*)d_ws;
    size_t off = 0;
    auto alloc = [&](size_t bytes) { void* p = ws + off; off += (bytes + 255) & ~(size_t)255; return p; };
    float* feats0   = (float*)alloc((size_t)B_ * N1_ * PROJ_ * 4);
    float* centers1 = (float*)alloc((size_t)B_ * M1_ * 3 * 4);
    int*   nidx1    = (int*)  alloc((size_t)B_ * M1_ * KNN_ * 4);
    float* feats1   = (float*)alloc((size_t)B_ * M1_ * C1_ * 4);
    float* centers2 = (float*)alloc((size_t)B_ * M2_ * 3 * 4);
    int*   nidx2    = (int*)  alloc((size_t)B_ * M2_ * KNN_ * 4);
    float* feats2   = (float*)alloc((size_t)B_ * M2_ * C2_ * 4);
    unsigned* prog  = (unsigned*)alloc(B_ * 16 * 4);   // 64B-strided flags
    (void)in_sizes; (void)n_in; (void)out_size; (void)ws_size;

    // zero chunk-progress flags each launch (graph replays must not see stale)
    hipMemsetAsync(prog, 0, B_ * 16 * 4, stream);

    // 1: fps1 (blocks 0..3) + proj (8192) + chunk-pipelined knn1 (8192)
    mega1_kernel<<<dim3(B_ + PROJ_BLKS_ + KNN_BLKS_), dim3(512), 0, stream>>>(
        xyz, Wp, bp, feats0, centers1, nidx1, prog);
    // 2: MLP level 1 (blocks 4..) + FPS stage 2 (blocks 0..3)
    sa1_kernel<<<dim3(B_ + B_ * M1_), dim3(C1_), 0, stream>>>(
        xyz, feats0, centers1, nidx1, W1a, b1a, W1b, b1b, feats1, centers2);
    // 3: kNN level 2
    knn_kernel<M1_, M2_><<<dim3(B_ * M2_), dim3(64), 0, stream>>>(centers1, centers2, nidx2);
    // 4: MLP level 2
    group_mlp_kernel<M1_, C1_, C2_, M2_><<<dim3(B_ * M2_), dim3(C2_), 0, stream>>>(
        centers1, feats1, centers2, nidx2, W2a, b2a, W2b, b2b, feats2);
    // 5: head
    head_kernel<<<dim3(B_), dim3(256), 0, stream>>>(feats2, Wd1, bd1, Wd2, bd2, out);
}